// Round 13
// baseline (1122.493 us; speedup 1.0000x reference)
//
#include <hip/hip_runtime.h>
#include <cstdio>

// ---- problem constants (fixed by setup_inputs) ----
#define B_   256
#define L_   512
#define A_   40
#define FD_  78
#define FT_  54
#define LD_  128
#define P_   513            // L+1
#define ND_  (B_*A_)        // 10240 drug nodes
#define N2_  (B_*P_)        // 131328 protein nodes (= 1026*128, %128==0)
#define EB_  2046           // protein edges per batch: 2*(L-1)+2*L

typedef __attribute__((ext_vector_type(8))) short short8;
typedef __attribute__((ext_vector_type(4))) float floatx4;
typedef unsigned short u16;

__device__ __forceinline__ short f2bf(float f) {
    union { float f; unsigned u; } v; v.f = f;
    unsigned u = v.u;
    u += 0x7fff + ((u >> 16) & 1);   // round-to-nearest-even
    return (short)(u >> 16);
}
__device__ __forceinline__ float bf2f(u16 s) {
    union { unsigned u; float f; } v; v.u = ((unsigned)s) << 16; return v.f;
}

#define TBK 32
#define LDK 40   // LDS row stride in shorts: 80B (16B-aligned; 2-way bank alias free)
#define CSP 260  // fp32 epilogue-staging row stride (floats)

// LDS-only barrier: waits LDS ops, does NOT drain vmcnt -> global loads
// stay in flight across the barrier.  Correctness-verified rounds 6-8.
#define SYNC_LDS asm volatile("s_waitcnt lgkmcnt(0)\n\ts_barrier" ::: "memory")

// =====================================================================
// FUSED DRUG BRANCH (round-10 verified config: 512 threads, DR=20).
// Row-split: thread (half, col) computes 20 of the 40 rows of column
// col (acc[20]) -> 8 waves/block = 2 waves/SIMD.  r0 in {0,20} keeps
// the 20-float LDS reads 80B-aligned -> ds_read_b128 x5 (round-11's
// DR=10 broke alignment and doubled LDS instruction count: 218us).
// Aggregation boundary (rows 19<->20) exchanged pre-agg via LDS.
// =====================================================================
#define DR_ 20
__global__ __launch_bounds__(512) void drug_fused_k(
    const float* __restrict__ drug_x,
    const float* __restrict__ W_c1d, const float* __restrict__ b_c1d,
    const float* __restrict__ W_c2d, const float* __restrict__ b_c2d,
    const float* __restrict__ W_rd_g, const float* __restrict__ b_rd_g,
    const float* __restrict__ W_rd_l,
    float* __restrict__ xg)
{
    __shared__ float Xb[2][156 * 40];      // 49.9 KB ping-pong, XT[k][r]
    __shared__ float bndA[256];            // pre-agg acc at row 19 (half 0)
    __shared__ float bndB[256];            // pre-agg acc at row 20 (half 1)
    const int b = blockIdx.x, t = threadIdx.x;
    const int col = t & 255, half = t >> 8;
    const int r0 = half * DR_;
    const float DI2 = 0.70710678118654752f;
    const float DI3 = 0.57735026918962576f;

    // stage drug_x[b] ([40][78] row-major) -> Xb[0] transposed
    for (int idx = t; idx < 40 * 78; idx += 512) {
        int r = idx / 78, k = idx - r * 78;
        Xb[0][k * 40 + r] = drug_x[(size_t)(b * A_ + r) * FD_ + k];
    }
    __syncthreads();

    float acc[DR_], hn[DR_];

    // acc[r] = sum_k XT[src][k][r0+r] * W[k][col]
    auto gemm_cols = [&](const float* __restrict__ Wp, int K, int N, int SRC) {
#pragma unroll
        for (int r = 0; r < DR_; ++r) acc[r] = 0.f;
        if (col < N) {
            for (int k = 0; k < K; ++k) {
                float w = Wp[(size_t)k * N + col];
                const float* xp = &Xb[SRC][k * 40 + r0];
#pragma unroll
                for (int r = 0; r < DR_; ++r)
                    acc[r] = fmaf(xp[r], w, acc[r]);
            }
        }
    };

    // graph agg (+bias, relu) with cross-half boundary exchange; store DST
    auto agg_store = [&](const float* __restrict__ bias, int N, int DST) {
        if (col < N) {
            if (half == 0) bndA[col] = acc[DR_ - 1];   // row 19
            else           bndB[col] = acc[0];         // row 20
        }
        __syncthreads();
        if (col < N) {
            float bi = bias[col];
#pragma unroll
            for (int r = 0; r < DR_; ++r) {
                int gr = r0 + r;
                float da = (gr == 0 || gr == A_ - 1) ? DI2 : DI3;
                float v = da * da * acc[r] + bi;
                if (gr > 0) {
                    float pv = (r > 0) ? acc[r - 1] : bndA[col];
                    v += ((gr - 1 == 0) ? DI2 : DI3) * da * pv;
                }
                if (gr < A_ - 1) {
                    float nv = (r < DR_ - 1) ? acc[r + 1] : bndB[col];
                    v += ((gr + 1 == A_ - 1) ? DI2 : DI3) * da * nv;
                }
                hn[r] = fmaxf(v, 0.f);
            }
#pragma unroll
            for (int r = 0; r < DR_; ++r) Xb[DST][col * 40 + r0 + r] = hn[r];
        }
        __syncthreads();
    };

    // conv1: 78 -> 78   (Xb0 -> Xb1)
    gemm_cols(W_c1d, FD_, FD_, 0);
    agg_store(b_c1d, FD_, 1);
    // conv2: 78 -> 156  (Xb1 -> Xb0)
    gemm_cols(W_c2d, FD_, 2 * FD_, 1);
    agg_store(b_c2d, 2 * FD_, 0);

    // 4 res-blocks
    for (int it = 0; it < 4; ++it) {
        gemm_cols(W_rd_g, 2 * FD_, 2 * FD_, 0);
        agg_store(b_rd_g, 2 * FD_, 1);
        gemm_cols(W_rd_l, 2 * FD_, 2 * FD_, 1);
        if (col < 2 * FD_) {
#pragma unroll
            for (int r = 0; r < DR_; ++r)
                hn[r] = fmaxf(acc[r] + Xb[0][col * 40 + r0 + r], 0.f);
        }
        __syncthreads();           // all reads of Xb0/Xb1 done
        if (col < 2 * FD_) {
#pragma unroll
            for (int r = 0; r < DR_; ++r) Xb[0][col * 40 + r0 + r] = hn[r];
        }
        __syncthreads();
    }

    // max-pool over 40 nodes (hn holds this thread's final rows)
    if (col < 2 * FD_) {
        float m = -INFINITY;
#pragma unroll
        for (int r = 0; r < DR_; ++r) m = fmaxf(m, hn[r]);
        if (half == 0) bndA[col] = m; else bndB[col] = m;
    }
    __syncthreads();
    if (half == 0 && col < 2 * FD_)
        xg[(size_t)b * (2 * FD_) + col] = fmaxf(bndA[col], bndB[col]);
}

// =====================================================================
// MFMA GEMM (fp32 A): C_fp32 = A[M,K]fp32 @ W (WT[N][Kp] bf16). For attention.
// =====================================================================
__global__ __launch_bounds__(256) void gemm_mfma_k(
    const float* __restrict__ A, const short* __restrict__ WT,
    float* __restrict__ C, int M, int N, int K, int Kp)
{
    __shared__ short As[128 * LDK];
    __shared__ short Bs[128 * LDK];
    const int bm = blockIdx.y * 128;
    const int bn = blockIdx.x * 128;
    const int tid  = threadIdx.x;
    const int wave = tid >> 6, lane = tid & 63;
    const int wm = (wave >> 1) * 64, wn = (wave & 1) * 64;
    const int lrow = lane & 15, quad = lane >> 4;

    floatx4 acc[4][4] = {};

    for (int k0 = 0; k0 < Kp; k0 += TBK) {
#pragma unroll
        for (int it = 0; it < 2; ++it) {
            int g   = it * 256 + tid;
            int row = g >> 2, kg = g & 3;
            int kb  = k0 + kg * 8;
            const float* arow = A + (size_t)(bm + row) * K + kb;
            short8 av;
#pragma unroll
            for (int j = 0; j < 8; ++j) av[j] = (kb + j < K) ? f2bf(arow[j]) : (short)0;
            *(short8*)&As[row * LDK + kg * 8] = av;
            *(short8*)&Bs[row * LDK + kg * 8] = *(const short8*)(WT + (size_t)(bn + row) * Kp + kb);
        }
        __syncthreads();
        short8 af[4], bfv[4];
#pragma unroll
        for (int i = 0; i < 4; ++i)
            af[i] = *(short8*)&As[(wm + i * 16 + lrow) * LDK + quad * 8];
#pragma unroll
        for (int j = 0; j < 4; ++j)
            bfv[j] = *(short8*)&Bs[(wn + j * 16 + lrow) * LDK + quad * 8];
#pragma unroll
        for (int i = 0; i < 4; ++i)
#pragma unroll
            for (int j = 0; j < 4; ++j)
                acc[i][j] = __builtin_amdgcn_mfma_f32_16x16x32_bf16(af[i], bfv[j], acc[i][j], 0, 0, 0);
        __syncthreads();
    }
#pragma unroll
    for (int i = 0; i < 4; ++i) {
        int grow0 = bm + wm + i * 16 + quad * 4;
#pragma unroll
        for (int j = 0; j < 4; ++j) {
            int col = bn + wn + j * 16 + lrow;
            size_t base = (size_t)grow0 * N + col;
#pragma unroll
            for (int r = 0; r < 4; ++r)
                C[base + (size_t)r * N] = acc[i][j][r];
        }
    }
}

// =====================================================================
// MFMA GEMM (bf16 A), 128x128 tile. For conv1 (N=128, K small).
// =====================================================================
__global__ __launch_bounds__(256) void gemm_bb_k(
    const u16* __restrict__ A, int lda, const short* __restrict__ WT, int Kp,
    const u16* __restrict__ resid, u16* __restrict__ C, int N, int act)
{
    __shared__ short As[128 * LDK];
    __shared__ short Bs[128 * LDK];
    const int bm = blockIdx.y * 128;
    const int bn = blockIdx.x * 128;
    const int tid  = threadIdx.x;
    const int wave = tid >> 6, lane = tid & 63;
    const int wm = (wave >> 1) * 64, wn = (wave & 1) * 64;
    const int lrow = lane & 15, quad = lane >> 4;

    floatx4 acc[4][4] = {};

    for (int k0 = 0; k0 < Kp; k0 += TBK) {
#pragma unroll
        for (int it = 0; it < 2; ++it) {
            int g   = it * 256 + tid;
            int row = g >> 2, kg = g & 3;
            int kb  = k0 + kg * 8;
            *(short8*)&As[row * LDK + kg * 8] = *(const short8*)(A + (size_t)(bm + row) * lda + kb);
            *(short8*)&Bs[row * LDK + kg * 8] = *(const short8*)(WT + (size_t)(bn + row) * Kp + kb);
        }
        __syncthreads();
        short8 af[4], bfv[4];
#pragma unroll
        for (int i = 0; i < 4; ++i)
            af[i] = *(short8*)&As[(wm + i * 16 + lrow) * LDK + quad * 8];
#pragma unroll
        for (int j = 0; j < 4; ++j)
            bfv[j] = *(short8*)&Bs[(wn + j * 16 + lrow) * LDK + quad * 8];
#pragma unroll
        for (int i = 0; i < 4; ++i)
#pragma unroll
            for (int j = 0; j < 4; ++j)
                acc[i][j] = __builtin_amdgcn_mfma_f32_16x16x32_bf16(af[i], bfv[j], acc[i][j], 0, 0, 0);
        __syncthreads();
    }
#pragma unroll
    for (int i = 0; i < 4; ++i) {
        int grow0 = bm + wm + i * 16 + quad * 4;
#pragma unroll
        for (int j = 0; j < 4; ++j) {
            int col = bn + wn + j * 16 + lrow;
            size_t base = (size_t)grow0 * N + col;
#pragma unroll
            for (int r = 0; r < 4; ++r) {
                float v = acc[i][j][r];
                size_t idx = base + (size_t)r * N;
                if (resid) v += bf2f(resid[idx]);
                if (act)   v = fmaxf(v, 0.f);
                C[idx] = (u16)f2bf(v);
            }
        }
    }
}

// =====================================================================
// MFMA GEMM, 64x256 tile, N=256, K = KT*32.  Round-7/8 verified loop;
// round-13: __launch_bounds__(256,3) — regs used 80+64acc=144 <= 170
// cap, allows 3 blocks/CU (was 2; occupancy 26% -> predicted ~37%).
// Optional Wacc epilogue (drug-row partial sums).
// =====================================================================
template<int KT>
__global__ __launch_bounds__(256, 3) void gemm_n256pw_k(
    const u16* __restrict__ A, const short* __restrict__ WT,
    const u16* __restrict__ resid, u16* __restrict__ C, int act,
    const float* __restrict__ cInF, float* __restrict__ Wacc)
{
    constexpr int K = KT * TBK;
    __shared__ short As[64 * LDK];      // 5 KB
    __shared__ float Cs[16 * CSP];      // 16.25 KB epilogue staging
    const int bm = blockIdx.x * 64;
    const int tid  = threadIdx.x;
    const int wave = tid >> 6, lane = tid & 63;
    const int wn = wave * 64;
    const int lrow = lane & 15, quad = lane >> 4;
    const int srow = tid >> 2, skg = tid & 3;   // staging row / k-group

    floatx4 acc[4][4] = {};

    short8 aR[KT];
#pragma unroll
    for (int kt = 0; kt < KT; ++kt)
        aR[kt] = *(const short8*)(A + (size_t)(bm + srow) * K + kt * TBK + skg * 8);

    const short* bp0 = WT + (size_t)(wn +  0 + lrow) * K + quad * 8;
    const short* bp1 = WT + (size_t)(wn + 16 + lrow) * K + quad * 8;
    const short* bp2 = WT + (size_t)(wn + 32 + lrow) * K + quad * 8;
    const short* bp3 = WT + (size_t)(wn + 48 + lrow) * K + quad * 8;
    short8 bfv[2][4];
    bfv[0][0] = *(const short8*)bp0;
    bfv[0][1] = *(const short8*)bp1;
    bfv[0][2] = *(const short8*)bp2;
    bfv[0][3] = *(const short8*)bp3;

#pragma unroll
    for (int kt = 0; kt < KT; ++kt) {
        const int cur = kt & 1, nxt = cur ^ 1;
        *(short8*)&As[srow * LDK + skg * 8] = aR[kt];
        SYNC_LDS;
        if (kt + 1 < KT) {
            const int kn = (kt + 1) * TBK;
            bfv[nxt][0] = *(const short8*)(bp0 + kn);
            bfv[nxt][1] = *(const short8*)(bp1 + kn);
            bfv[nxt][2] = *(const short8*)(bp2 + kn);
            bfv[nxt][3] = *(const short8*)(bp3 + kn);
        }
        short8 af[4];
#pragma unroll
        for (int i = 0; i < 4; ++i)
            af[i] = *(short8*)&As[(i * 16 + lrow) * LDK + quad * 8];
#pragma unroll
        for (int i = 0; i < 4; ++i)
#pragma unroll
            for (int j = 0; j < 4; ++j)
                acc[i][j] = __builtin_amdgcn_mfma_f32_16x16x32_bf16(af[i], bfv[cur][j], acc[i][j], 0, 0, 0);
        SYNC_LDS;
    }

    if (cInF) {
        const int b0 = bm / P_;
        const int b1 = (bm + 63) / P_;
        float s0[4] = {0.f, 0.f, 0.f, 0.f};
        float s1[4] = {0.f, 0.f, 0.f, 0.f};
#pragma unroll
        for (int i = 0; i < 4; ++i) {
#pragma unroll
            for (int r = 0; r < 4; ++r) {
                int grow = bm + i * 16 + quad * 4 + r;
                float ci = cInF[grow];
                bool hi = (grow / P_) != b0;
#pragma unroll
                for (int j = 0; j < 4; ++j) {
                    float v = ci * acc[i][j][r];
                    if (hi) s1[j] += v; else s0[j] += v;
                }
            }
        }
#pragma unroll
        for (int j = 0; j < 4; ++j) {
            s0[j] += __shfl_xor(s0[j], 16);
            s0[j] += __shfl_xor(s0[j], 32);
            s1[j] += __shfl_xor(s1[j], 16);
            s1[j] += __shfl_xor(s1[j], 32);
        }
        if (quad == 0) {
#pragma unroll
            for (int j = 0; j < 4; ++j) {
                int col = wn + j * 16 + lrow;
                atomicAdd(&Wacc[(size_t)b0 * 256 + col], s0[j]);
                if (b1 != b0) atomicAdd(&Wacc[(size_t)b1 * 256 + col], s1[j]);
            }
        }
    }

    // staged C epilogue: fp32 LDS re-layout -> coalesced short8 IO
    const int erl = tid >> 4;
    const int ecc = (tid & 15) * 16;
#pragma unroll
    for (int i = 0; i < 4; ++i) {
#pragma unroll
        for (int j = 0; j < 4; ++j)
#pragma unroll
            for (int r = 0; r < 4; ++r)
                Cs[(quad * 4 + r) * CSP + wn + j * 16 + lrow] = acc[i][j][r];
        SYNC_LDS;
        const int grow = bm + i * 16 + erl;
        const size_t gbase = (size_t)grow * 256 + ecc;
#pragma unroll
        for (int h = 0; h < 2; ++h) {
            const float* cp = &Cs[erl * CSP + ecc + h * 8];
            short8 ov;
            if (resid) {
                short8 rv = *(const short8*)(resid + gbase + h * 8);
#pragma unroll
                for (int e = 0; e < 8; ++e) {
                    float v = cp[e] + bf2f((u16)rv[e]);
                    if (act) v = fmaxf(v, 0.f);
                    ov[e] = f2bf(v);
                }
            } else {
#pragma unroll
                for (int e = 0; e < 8; ++e) {
                    float v = cp[e];
                    if (act) v = fmaxf(v, 0.f);
                    ov[e] = f2bf(v);
                }
            }
            *(short8*)(C + gbase + h * 8) = ov;
        }
        SYNC_LDS;
    }
}

// =====================================================================
// Fused aggregation + l-GEMM (round-7/8 verified loop; launch_bounds
// (256,3) as above).
// =====================================================================
template<int KT>
__global__ __launch_bounds__(256, 3) void gemm_aggl_k(
    const u16* __restrict__ U, const short* __restrict__ WT,
    const float* __restrict__ cPc, const float* __restrict__ cNc,
    const float* __restrict__ cDc, const float* __restrict__ cSc,
    const float* __restrict__ Wacc, const float* __restrict__ bias,
    const u16* __restrict__ resid, u16* __restrict__ C)
{
    constexpr int K = KT * TBK;
    __shared__ short As[64 * LDK];      // 5 KB
    __shared__ float Cs[16 * CSP];      // 16.25 KB epilogue staging
    const int bm = blockIdx.x * 64;
    const int tid  = threadIdx.x;
    const int wave = tid >> 6, lane = tid & 63;
    const int wn = wave * 64;
    const int lrow = lane & 15, quad = lane >> 4;
    const int srow = tid >> 2, skg = tid & 3;

    const int r    = bm + srow;
    const int bl   = r / P_;
    const int irow = r - bl * P_;
    const bool isD = (irow == L_);
    const size_t rD = (size_t)bl * P_ + L_;
    const int rm = (r == 0) ? 0 : r - 1;            // cP==0 at i==0
    const int rp = (r == N2_ - 1) ? r : r + 1;      // cN==0 at i==L-1
    const float cs = cSc[r];
    const float cp = isD ? 0.f : cPc[r];
    const float cn = isD ? 0.f : cNc[r];
    const float cd = isD ? 0.f : cDc[r];
    const float* wrow = Wacc + (size_t)bl * 256;

    floatx4 acc[4][4] = {};

    const u16* uSp = U + (size_t)r  * K + skg * 8;
    const u16* uMp = U + (size_t)rm * K + skg * 8;
    const u16* uPp = U + (size_t)rp * K + skg * 8;
    const u16* uDp = U + rD * K + skg * 8;

    short8 uS[KT];
#pragma unroll
    for (int kt = 0; kt < KT; ++kt) uS[kt] = *(const short8*)(uSp + kt * TBK);
    short8 uM = *(const short8*)uMp;
    short8 uP = *(const short8*)uPp;
    short8 uD = *(const short8*)uDp;

    const short* bp0 = WT + (size_t)(wn +  0 + lrow) * K + quad * 8;
    const short* bp1 = WT + (size_t)(wn + 16 + lrow) * K + quad * 8;
    const short* bp2 = WT + (size_t)(wn + 32 + lrow) * K + quad * 8;
    const short* bp3 = WT + (size_t)(wn + 48 + lrow) * K + quad * 8;

#pragma unroll
    for (int kt = 0; kt < KT; ++kt) {
        const int kb = kt * TBK + skg * 8;
        float4 bi0 = *(const float4*)(bias + kb);
        float4 bi1 = *(const float4*)(bias + kb + 4);
        float bv[8] = {bi0.x, bi0.y, bi0.z, bi0.w, bi1.x, bi1.y, bi1.z, bi1.w};
        if (isD) {
            float4 w0 = *(const float4*)(wrow + kb);
            float4 w1 = *(const float4*)(wrow + kb + 4);
            bv[0] += w0.x; bv[1] += w0.y; bv[2] += w0.z; bv[3] += w0.w;
            bv[4] += w1.x; bv[5] += w1.y; bv[6] += w1.z; bv[7] += w1.w;
        }
        short8 av;
#pragma unroll
        for (int e = 0; e < 8; ++e) {
            float v = cs * bf2f((u16)uS[kt][e]) + cp * bf2f((u16)uM[e])
                    + cn * bf2f((u16)uP[e]) + cd * bf2f((u16)uD[e]) + bv[e];
            av[e] = f2bf(fmaxf(v, 0.f));
        }
        *(short8*)&As[srow * LDK + skg * 8] = av;
        const int kc = kt * TBK;
        short8 bfv0 = *(const short8*)(bp0 + kc);
        short8 bfv1 = *(const short8*)(bp1 + kc);
        short8 bfv2 = *(const short8*)(bp2 + kc);
        short8 bfv3 = *(const short8*)(bp3 + kc);
        SYNC_LDS;
        if (kt + 1 < KT) {
            const int kn = (kt + 1) * TBK;
            uM = *(const short8*)(uMp + kn);
            uP = *(const short8*)(uPp + kn);
            uD = *(const short8*)(uDp + kn);
        }
        short8 af[4];
#pragma unroll
        for (int i = 0; i < 4; ++i)
            af[i] = *(short8*)&As[(i * 16 + lrow) * LDK + quad * 8];
#pragma unroll
        for (int i = 0; i < 4; ++i) {
            acc[i][0] = __builtin_amdgcn_mfma_f32_16x16x32_bf16(af[i], bfv0, acc[i][0], 0, 0, 0);
            acc[i][1] = __builtin_amdgcn_mfma_f32_16x16x32_bf16(af[i], bfv1, acc[i][1], 0, 0, 0);
            acc[i][2] = __builtin_amdgcn_mfma_f32_16x16x32_bf16(af[i], bfv2, acc[i][2], 0, 0, 0);
            acc[i][3] = __builtin_amdgcn_mfma_f32_16x16x32_bf16(af[i], bfv3, acc[i][3], 0, 0, 0);
        }
        SYNC_LDS;
    }

    const int erl = tid >> 4;
    const int ecc = (tid & 15) * 16;
#pragma unroll
    for (int i = 0; i < 4; ++i) {
#pragma unroll
        for (int j = 0; j < 4; ++j)
#pragma unroll
            for (int r2 = 0; r2 < 4; ++r2)
                Cs[(quad * 4 + r2) * CSP + wn + j * 16 + lrow] = acc[i][j][r2];
        SYNC_LDS;
        const int grow = bm + i * 16 + erl;
        const size_t gbase = (size_t)grow * 256 + ecc;
#pragma unroll
        for (int h = 0; h < 2; ++h) {
            const float* cp2 = &Cs[erl * CSP + ecc + h * 8];
            short8 rv = *(const short8*)(resid + gbase + h * 8);
            short8 ov;
#pragma unroll
            for (int e = 0; e < 8; ++e) {
                float v = cp2[e] + bf2f((u16)rv[e]);
                ov[e] = f2bf(fmaxf(v, 0.f));
            }
            *(short8*)(C + gbase + h * 8) = ov;
        }
        SYNC_LDS;
    }
}

static inline void gemm_n256(const u16* A, int K, const short* WT,
                             const u16* resid, u16* C, int act,
                             const float* cInF, float* Wacc, hipStream_t s)
{
    dim3 g(N2_ / 64), b(256);
    if (K == 128)
        hipLaunchKernelGGL((gemm_n256pw_k<4>), g, b, 0, s, A, WT, resid, C, act, cInF, Wacc);
    else
        hipLaunchKernelGGL((gemm_n256pw_k<8>), g, b, 0, s, A, WT, resid, C, act, cInF, Wacc);
}

// one-time weight transpose+cast: WT[n*Kp+k] = bf16(W[k*Nreal+n]), zero padded
__global__ void wt_cvt_k(const float* __restrict__ W, short* __restrict__ WT,
                         int K, int Nreal, int Kp, int Ntot)
{
    int idx = blockIdx.x * 256 + threadIdx.x;
    if (idx >= Ntot * Kp) return;
    int n = idx / Kp, k = idx - n * Kp;
    WT[idx] = (k < K && n < Nreal) ? f2bf(W[(size_t)k * Nreal + n]) : (short)0;
}

// =====================================================================
// Split-K fp32 GEMM for small-M (M=256) head GEMMs.
// =====================================================================
#define BM 64
#define BN 64
#define BKK 16
__global__ __launch_bounds__(256) void gemm_skA_k(
    const float* __restrict__ Amat, const float* __restrict__ Wmat,
    float* __restrict__ part, int M, int N, int K, int Kc)
{
    __shared__ float As[BKK][BM + 4];
    __shared__ float Ws[BKK][BN];
    const int bm = blockIdx.y * BM;
    const int bn = blockIdx.x * BN;
    const int sk = blockIdx.z;
    const int kb0  = sk * Kc;
    const int kend = min(K, kb0 + Kc);
    const int tx = threadIdx.x, ty = threadIdx.y;
    const int tid = ty * 16 + tx;
    float acc[4][4] = {};

    for (int k0 = kb0; k0 < kend; k0 += BKK) {
#pragma unroll
        for (int j = 0; j < 4; ++j) {
            int l = tid + 256 * j;
            int m = l >> 4, kk = l & 15;
            int gm = bm + m, gk = k0 + kk;
            As[kk][m] = (gm < M && gk < kend) ? Amat[(size_t)gm * K + gk] : 0.f;
        }
#pragma unroll
        for (int j = 0; j < 4; ++j) {
            int l = tid + 256 * j;
            int kk = l >> 6, n = l & 63;
            int gk = k0 + kk, gn = bn + n;
            Ws[kk][n] = (gk < kend && gn < N) ? Wmat[(size_t)gk * N + gn] : 0.f;
        }
        __syncthreads();
#pragma unroll
        for (int k = 0; k < BKK; ++k) {
            float4 a4 = *(const float4*)&As[k][ty * 4];
            float4 w4 = *(const float4*)&Ws[k][tx * 4];
            float av[4] = {a4.x, a4.y, a4.z, a4.w};
            float wv[4] = {w4.x, w4.y, w4.z, w4.w};
#pragma unroll
            for (int i = 0; i < 4; ++i)
#pragma unroll
                for (int j = 0; j < 4; ++j)
                    acc[i][j] = fmaf(av[i], wv[j], acc[i][j]);
        }
        __syncthreads();
    }
#pragma unroll
    for (int i = 0; i < 4; ++i) {
        int gm = bm + ty * 4 + i;
        if (gm >= M) continue;
#pragma unroll
        for (int j = 0; j < 4; ++j) {
            int gn = bn + tx * 4 + j;
            if (gn >= N) continue;
            part[((size_t)sk * M + gm) * N + gn] = acc[i][j];
        }
    }
}

__global__ void gemm_skB_k(const float* __restrict__ part, const float* __restrict__ bias,
                           float* __restrict__ C, int M, int N, int SK, int act)
{
    int idx = blockIdx.x * 256 + threadIdx.x;
    if (idx >= M * N) return;
    int n = idx % N;
    float v = bias ? bias[n] : 0.f;
    for (int s = 0; s < SK; ++s) v += part[(size_t)s * M * N + idx];
    if (act) v = fmaxf(v, 0.f);
    C[idx] = v;
}

static inline void gemm_sk(const float* A, const float* W, const float* bias,
                           float* C, float* skbuf, int M, int N, int K, int SK, int act,
                           hipStream_t s)
{
    int Kc = (K + SK - 1) / SK;
    dim3 g((N + 63) / 64, (M + 63) / 64, SK), b(16, 16);
    hipLaunchKernelGGL(gemm_skA_k, g, b, 0, s, A, W, skbuf, M, N, K, Kc);
    hipLaunchKernelGGL(gemm_skB_k, dim3((M * N + 255) / 256), dim3(256), 0, s,
                       skbuf, bias, C, M, N, SK, act);
}

// =====================================================================
// Attention epilogue + softmax
// =====================================================================
__global__ __launch_bounds__(256) void att_dot_k(
    const float* __restrict__ Hs, const float* __restrict__ b1,
    const float* __restrict__ W2, const float* __restrict__ b2,
    float* __restrict__ scores)
{
    int w = threadIdx.x >> 6, lane = threadIdx.x & 63;
    float b1v = (lane < FT_) ? b1[lane] : 0.f;
    float w2v = (lane < FT_) ? W2[lane] : 0.f;
    float b2v = b2[0];
    int base = blockIdx.x * 64 + w * 16;
    for (int rr = 0; rr < 16; ++rr) {
        int r = base + rr;
        float v = 0.f;
        if (lane < FT_) v = tanhf(Hs[(size_t)r * 128 + lane] + b1v) * w2v;
#pragma unroll
        for (int o = 32; o; o >>= 1) v += __shfl_down(v, o);
        if (lane == 0) {
            int bl = r / P_, i = r - bl * P_;
            if (i < L_) scores[bl * L_ + i] = v + b2v;
        }
    }
}

__global__ __launch_bounds__(512) void softmax_k(
    const float* __restrict__ scores, float* __restrict__ att, float* __restrict__ attsum)
{
    int b = blockIdx.x, t = threadIdx.x;
    __shared__ float sm[8];
    __shared__ float bcast;
    float v = scores[b * L_ + t];
    float m = v;
#pragma unroll
    for (int o = 32; o; o >>= 1) m = fmaxf(m, __shfl_down(m, o));
    if ((t & 63) == 0) sm[t >> 6] = m;
    __syncthreads();
    if (t == 0) { float mm = sm[0]; for (int i = 1; i < 8; ++i) mm = fmaxf(mm, sm[i]); bcast = mm; }
    __syncthreads();
    float mx = bcast;
    float e = expf(v - mx);
    float s = e;
#pragma unroll
    for (int o = 32; o; o >>= 1) s += __shfl_down(s, o);
    __syncthreads();
    if ((t & 63) == 0) sm[t >> 6] = s;
    __syncthreads();
    if (t == 0) { float ss = 0; for (int i = 0; i < 8; ++i) ss += sm[i]; bcast = ss; }
    __syncthreads();
    float a = e / bcast;
    att[b * L_ + t] = a;
    float s2 = a;
#pragma unroll
    for (int o = 32; o; o >>= 1) s2 += __shfl_down(s2, o);
    __syncthreads();
    if ((t & 63) == 0) sm[t >> 6] = s2;
    __syncthreads();
    if (t == 0) { float ss = 0; for (int i = 0; i < 8; ++i) ss += sm[i]; attsum[b] = ss; }
}

// =====================================================================
// Protein GCN coefficients
// =====================================================================
__global__ void coef_deg_k(const float* __restrict__ prot_ea, const float* __restrict__ att,
                           const float* __restrict__ attsum, float* __restrict__ dinv, int use_ea)
{
    int r = blockIdx.x * 256 + threadIdx.x;
    if (r >= N2_) return;
    int b = r / P_, i = r - b * P_;
    float deg;
    if (i == L_) {
        deg = 1.f + (use_ea ? attsum[b] : (float)L_);
    } else {
        float wP = (i >= 1)      ? (use_ea ? prot_ea[b * EB_ + (i - 1)]   : 1.f) : 0.f;
        float wN = (i <= L_ - 2) ? (use_ea ? prot_ea[b * EB_ + 511 + i]   : 1.f) : 0.f;
        float wD = use_ea ? att[b * L_ + i] : 1.f;
        deg = 1.f + wP + wN + wD;
    }
    dinv[r] = rsqrtf(deg);
}

__global__ void coef_k(const float* __restrict__ dinv, const float* __restrict__ prot_ea,
                       const float* __restrict__ att, float* __restrict__ cP, float* __restrict__ cN,
                       float* __restrict__ cD, float* __restrict__ cS, float* __restrict__ cIn,
                       float* __restrict__ cInF, int use_ea)
{
    int r = blockIdx.x * 256 + threadIdx.x;
    if (r >= N2_) return;
    int b = r / P_, i = r - b * P_;
    float di = dinv[r];
    cS[r] = di * di;
    if (i == L_) { cP[r] = 0.f; cN[r] = 0.f; cD[r] = 0.f; cInF[r] = 0.f; return; }
    float wP = (i >= 1)      ? (use_ea ? prot_ea[b * EB_ + (i - 1)] : 1.f) : 0.f;
    float wN = (i <= L_ - 2) ? (use_ea ? prot_ea[b * EB_ + 511 + i] : 1.f) : 0.f;
    float wD = use_ea ? att[b * L_ + i] : 1.f;
    float dD = dinv[b * P_ + L_];
    cP[r] = (i >= 1)      ? dinv[r - 1] * wP * di : 0.f;
    cN[r] = (i <= L_ - 2) ? dinv[r + 1] * wN * di : 0.f;
    cD[r] = dD * wD * di;
    float ci = di * wD * dD;
    cIn[b * L_ + i] = ci;
    cInF[r] = ci;
}

// =====================================================================
// Vectorized protein aggregation (bf16 in/out, fp32 math), short8 loads.
// (used for conv1/conv2 aggregation)
// =====================================================================
template<int F>
__global__ __launch_bounds__(256) void prot_agg_res_k(
    const u16* __restrict__ h, const float* __restrict__ cP,
    const float* __restrict__ cN, const float* __restrict__ cD,
    const float* __restrict__ cS, const float* __restrict__ cIn,
    const float* __restrict__ bias, u16* __restrict__ outp,
    float* __restrict__ Wacc)
{
    constexpr int G = F / 8;
    constexpr int RPB = 256 / G;
    __shared__ float pacc[RPB * F];     // 8 KB
    int t = threadIdx.x;
    int rl = t / G, g = t - rl * G;
    int base = blockIdx.x * RPB;
    int r = base + rl;
    int bl = r / P_, i = r - bl * P_;
    int f0 = g * 8;
    const u16* hs = h + (size_t)r * F + f0;
    if (i == L_) {
#pragma unroll
        for (int e = 0; e < 8; ++e) pacc[rl * F + f0 + e] = 0.f;
    } else {
        const u16* hd = h + ((size_t)bl * P_ + L_) * F + f0;
        float cs = cS[r], cd = cD[r], cp = cP[r], cn = cN[r];
        float ci = cIn[bl * L_ + i];
        short8 vs = *(const short8*)hs;
        short8 vd = *(const short8*)hd;
        short8 vp = *(const short8*)(hs - (i > 0 ? F : 0));   // cp==0 at i==0
        short8 vn = *(const short8*)(hs + F);                  // cn==0 at i==L-1
        short8 ov;
#pragma unroll
        for (int e = 0; e < 8; ++e) {
            float hv = bf2f((u16)vs[e]);
            pacc[rl * F + f0 + e] = ci * hv;
            float v = cs * hv + cd * bf2f((u16)vd[e]) + bias[f0 + e];
            v += cp * bf2f((u16)vp[e]);
            v += cn * bf2f((u16)vn[e]);
            ov[e] = f2bf(fmaxf(v, 0.f));
        }
        *(short8*)(outp + (size_t)r * F + f0) = ov;
    }
    __syncthreads();
    int f = t;
    if (f < F) {
        int b0   = base / P_;
        int bend = (base + RPB - 1) / P_;
        float s0 = 0.f, s1 = 0.f;
#pragma unroll
        for (int rr = 0; rr < RPB; ++rr) {
            float v = pacc[rr * F + f];
            if ((base + rr) / P_ == b0) s0 += v; else s1 += v;
        }
        atomicAdd(&Wacc[(size_t)b0 * F + f], s0);
        if (bend != b0) atomicAdd(&Wacc[(size_t)bend * F + f], s1);
    }
}

// finalize drug rows: V[drug] = relu(Wacc + cS*h[drug] + bias)
__global__ void drug_fin_k(const float* __restrict__ Wacc, const u16* __restrict__ h,
                           const float* __restrict__ cS, const float* __restrict__ bias,
                           u16* __restrict__ outp, int F)
{
    int bl = blockIdx.x, t = threadIdx.x;
    if (t >= F) return;
    size_t rD = (size_t)bl * P_ + L_;
    float v = Wacc[(size_t)bl * F + t] + cS[rD] * bf2f(h[rD * F + t]) + bias[t];
    outp[rD * F + t] = (u16)f2bf(fmaxf(v, 0.f));
}

// build bf16 conv1 input: Xin[N2][64], cols<54 = prot_x (drug rows from t2d), else 0
__global__ void xin_k(const float* __restrict__ prot_x, const float* __restrict__ t2d,
                      u16* __restrict__ Xin)
{
    int idx = blockIdx.x * 256 + threadIdx.x;
    if (idx >= N2_ * 64) return;
    int r = idx >> 6, t = idx & 63;
    int bl = r / P_, i = r - bl * P_;
    float v = 0.f;
    if (t < FT_) v = (i == L_) ? t2d[bl * FT_ + t] : prot_x[(size_t)r * FT_ + t];
    Xin[idx] = (u16)f2bf(v);
}

// per-batch max over residues + drug row extraction (vectorized, F=256)
__global__ __launch_bounds__(256) void x2g_bf2_k(const u16* __restrict__ X,
                                                 float* __restrict__ x2g, float* __restrict__ da)
{
    __shared__ float red[2048];
    int t = threadIdx.x;
    int rl = t >> 5, g = t & 31;
    int bl = blockIdx.x, f0 = g * 8;
    const u16* xb = X + (size_t)bl * P_ * 256;
    float m[8];
#pragma unroll
    for (int e = 0; e < 8; ++e) m[e] = -INFINITY;
    for (int j = rl; j < L_; j += 8) {
        short8 v = *(const short8*)(xb + (size_t)j * 256 + f0);
#pragma unroll
        for (int e = 0; e < 8; ++e) m[e] = fmaxf(m[e], bf2f((u16)v[e]));
    }
#pragma unroll
    for (int e = 0; e < 8; ++e) red[rl * 256 + f0 + e] = m[e];
    __syncthreads();
    if (rl == 0) {
        short8 vd = *(const short8*)(xb + (size_t)L_ * 256 + f0);
#pragma unroll
        for (int e = 0; e < 8; ++e) {
            float v = red[f0 + e];
            for (int rr = 1; rr < 8; ++rr) v = fmaxf(v, red[rr * 256 + f0 + e]);
            x2g[bl * 256 + f0 + e] = v;
            da[bl * 256 + f0 + e] = bf2f((u16)vd[e]);
        }
    }
}

__global__ void build_xc_k(const float* __restrict__ da, const float* __restrict__ x_chg,
                           const float* __restrict__ x2v, float* __restrict__ xc)
{
    int idx = blockIdx.x * 256 + threadIdx.x;
    if (idx >= B_ * 512) return;
    int b = idx >> 9, c = idx & 511;
    float v = (c < 256) ? fmaxf(da[b * 256 + c], x_chg[b * 256 + c])
                        : x2v[b * 256 + (c - 256)];
    xc[idx] = v;
}

__global__ __launch_bounds__(64) void out_k(const float* __restrict__ f2,
                                            const float* __restrict__ W,
                                            const float* __restrict__ bias,
                                            float* __restrict__ out)
{
    int row = blockIdx.x, t = threadIdx.x;
    float v = 0.f;
    for (int k = t; k < 512; k += 64) v = fmaf(f2[(size_t)row * 512 + k], W[k], v);
#pragma unroll
    for (int o = 32; o; o >>= 1) v += __shfl_down(v, o);
    if (t == 0) out[row] = v + bias[0];
}

// =====================================================================
extern "C" void kernel_launch(void* const* d_in, const int* in_sizes, int n_in,
                              void* d_out, int out_size, void* d_ws, size_t ws_size,
                              hipStream_t stream)
{
    const float* drug_x  = (const float*)d_in[0];
    const float* prot_x  = (const float*)d_in[3];
    const float* prot_ea = (const float*)d_in[6];
    const float* W_c1d = (const float*)d_in[7];   const float* b_c1d = (const float*)d_in[8];
    const float* W_c2d = (const float*)d_in[9];   const float* b_c2d = (const float*)d_in[10];
    const float* W_rd_g = (const float*)d_in[11]; const float* b_rd_g = (const float*)d_in[12];
    const float* W_rd_l = (const float*)d_in[13];
    const float* W_fg1d = (const float*)d_in[14]; const float* b_fg1d = (const float*)d_in[15];
    const float* W_fg2d = (const float*)d_in[16]; const float* b_fg2d = (const float*)d_in[17];
    const float* W_fg3d = (const float*)d_in[18]; const float* b_fg3d = (const float*)d_in[19];
    const float* W_att1 = (const float*)d_in[20]; const float* b_att1 = (const float*)d_in[21];
    const float* W_att2 = (const float*)d_in[22]; const float* b_att2 = (const float*)d_in[23];
    const float* W_c1t = (const float*)d_in[24];  const float* b_c1t = (const float*)d_in[25];
    const float* W_c2t = (const float*)d_in[26];  const float* b_c2t = (const float*)d_in[27];
    const float* W_rt_g = (const float*)d_in[28]; const float* b_rt_g = (const float*)d_in[29];
    const float* W_rt_l = (const float*)d_in[30];
    const float* W_fg1t = (const float*)d_in[31]; const float* b_fg1t = (const float*)d_in[32];
    const float* W_fg2t = (const float*)d_in[33]; const float* b_fg2t = (const float*)d_in[34];
    const float* W_fc1 = (const float*)d_in[35];  const float* b_fc1 = (const float*)d_in[36];
    const float* W_fc2 = (const float*)d_in[37];  const float* b_fc2 = (const float*)d_in[38];
    const float* W_out = (const float*)d_in[39];  const float* b_out = (const float*)d_in[40];
    float* out = (float*)d_out;

    float* ws = (float*)d_ws;
    size_t off = 0;
    auto alloc = [&](size_t n) {
        n = (n + 3) & ~(size_t)3;          // 16B alignment
        float* p = ws + off; off += n; return p;
    };

    // big bf16 activation buffers (full batch, width up to 256): 67.2 MB each
    u16* U = (u16*)alloc((size_t)N2_ * 128);
    u16* V = (u16*)alloc((size_t)N2_ * 128);
    u16* X = (u16*)alloc((size_t)N2_ * 128);
    u16* Xin = (u16*)alloc((size_t)N2_ * 32);    // [N2][64] bf16
    float* Hs = (float*)U;                        // fp32 attention scratch aliases U
    float* Wacc = alloc(B_ * 256);                // drug-row partial sums (fp32)
    float* xg    = alloc(B_ * 156);
    float* t1d   = alloc(B_ * 1024);
    float* t2d   = alloc(B_ * FT_);
    float* x_chg = alloc(B_ * 256);
    float* scores = alloc(B_ * 512);
    float* att    = alloc(B_ * 512);
    float* attsum = alloc(B_);
    float* dinvE = alloc(N2_);
    float* cPE = alloc(N2_); float* cNE = alloc(N2_); float* cDE = alloc(N2_); float* cSE = alloc(N2_);
    float* cInE = alloc(B_ * 512);
    float* cInFE = alloc(N2_);
    float* dinvO = alloc(N2_);
    float* cPO = alloc(N2_); float* cNO = alloc(N2_); float* cDO = alloc(N2_); float* cSO = alloc(N2_);
    float* cInO = alloc(B_ * 512);
    float* cInFO = alloc(N2_);
    float* x2g = alloc(B_ * 256);
    float* dafter = alloc(B_ * 256);
    float* t1t = alloc(B_ * 1024);
    float* x2v = alloc(B_ * 256);
    float* xc  = alloc(B_ * 512);
    float* f1  = alloc(B_ * 1024);
    float* f2  = alloc(B_ * 512);
    float* skbuf = alloc((size_t)2 * 1024 * 1024);
    // bf16 transposed weights
    short* WT_c1t = (short*)alloc(128 * 64 / 2);
    short* WT_c2t = (short*)alloc(256 * 128 / 2);
    short* WT_rtg = (short*)alloc(256 * 256 / 2);
    short* WT_rtl = (short*)alloc(256 * 256 / 2);
    short* WT_att = (short*)alloc(128 * 64 / 2);

    if (off * sizeof(float) > ws_size) {
        fprintf(stderr, "kernel_launch: workspace too small: need %zu, have %zu\n",
                off * sizeof(float), ws_size);
        return;
    }

    // ---------- one-time weight cast/transpose ----------
    hipLaunchKernelGGL(wt_cvt_k, dim3((128 * 64 + 255) / 256), dim3(256), 0, stream,  W_c1t, WT_c1t, FT_, 128, 64, 128);
    hipLaunchKernelGGL(wt_cvt_k, dim3((256 * 128 + 255) / 256), dim3(256), 0, stream, W_c2t, WT_c2t, 128, 256, 128, 256);
    hipLaunchKernelGGL(wt_cvt_k, dim3((256 * 256 + 255) / 256), dim3(256), 0, stream, W_rt_g, WT_rtg, 256, 256, 256, 256);
    hipLaunchKernelGGL(wt_cvt_k, dim3((256 * 256 + 255) / 256), dim3(256), 0, stream, W_rt_l, WT_rtl, 256, 256, 256, 256);
    hipLaunchKernelGGL(wt_cvt_k, dim3((128 * 64 + 255) / 256), dim3(256), 0, stream,  W_att1, WT_att, FT_, FT_, 64, 128);

    // ---------- drug branch: ONE fused kernel (10 layers + max-pool) ----------
    hipLaunchKernelGGL(drug_fused_k, dim3(B_), dim3(512), 0, stream,
                       drug_x, W_c1d, b_c1d, W_c2d, b_c2d, W_rd_g, b_rd_g, W_rd_l, xg);
    gemm_sk(xg,  W_fg1d, b_fg1d, t1d,   skbuf, B_, 1024, 156, 4, 1, stream);
    gemm_sk(t1d, W_fg2d, b_fg2d, t2d,   skbuf, B_, FT_, 1024, 16, 0, stream);
    gemm_sk(t2d, W_fg3d, b_fg3d, x_chg, skbuf, B_, 2 * LD_, FT_, 2, 1, stream);

    // ---------- attention (MFMA) ----------
    {
        dim3 g(1, N2_ / 128), b(256);
        hipLaunchKernelGGL(gemm_mfma_k, g, b, 0, stream, prot_x, WT_att, Hs, N2_, 128, FT_, 64);
    }
    hipLaunchKernelGGL(att_dot_k, dim3(N2_ / 64), dim3(256), 0, stream, Hs, b_att1, W_att2, b_att2, scores);
    hipLaunchKernelGGL(softmax_k, dim3(B_), dim3(512), 0, stream, scores, att, attsum);

    // ---------- protein GCN coefficients ----------
    hipLaunchKernelGGL(coef_deg_k, dim3((N2_ + 255) / 256), dim3(256), 0, stream, prot_ea, att, attsum, dinvE, 1);
    hipLaunchKernelGGL(coef_k, dim3((N2_ + 255) / 256), dim3(256), 0, stream, dinvE, prot_ea, att, cPE, cNE, cDE, cSE, cInE, cInFE, 1);
    hipLaunchKernelGGL(coef_deg_k, dim3((N2_ + 255) / 256), dim3(256), 0, stream, prot_ea, att, attsum, dinvO, 0);
    hipLaunchKernelGGL(coef_k, dim3((N2_ + 255) / 256), dim3(256), 0, stream, dinvO, prot_ea, att, cPO, cNO, cDO, cSO, cInO, cInFO, 0);

    // ---------- protein branch (full batch, bf16 activations) ----------
    hipLaunchKernelGGL(xin_k, dim3((N2_ * 64 + 255) / 256), dim3(256), 0, stream, prot_x, t2d, Xin);

    // conv1: Xin(64) -> U [N2][128]
    {
        dim3 g(1, N2_ / 128), b(256);
        hipLaunchKernelGGL(gemm_bb_k, g, b, 0, stream, Xin, 64, WT_c1t, 64,
                           (const u16*)nullptr, U, 128, 0);
    }
    // agg(E): U -> V (width 128), drug partials -> Wacc, finalize
    hipMemsetAsync(Wacc, 0, B_ * 128 * sizeof(float), stream);
    hipLaunchKernelGGL((prot_agg_res_k<128>), dim3(N2_ / 16), dim3(256), 0, stream,
                       U, cPE, cNE, cDE, cSE, cInE, b_c1t, V, Wacc);
    hipLaunchKernelGGL(drug_fin_k, dim3(B_), dim3(128), 0, stream, Wacc, U, cSE, b_c1t, V, 128);
    // conv2: V(128) -> U [N2][256]
    gemm_n256(V, 128, WT_c2t, (const u16*)nullptr, U, 0, nullptr, nullptr, stream);
    // agg(E): U -> X (width 256)
    hipMemsetAsync(Wacc, 0, B_ * 256 * sizeof(float), stream);
    hipLaunchKernelGGL((prot_agg_res_k<256>), dim3(N2_ / 8), dim3(256), 0, stream,
                       U, cPE, cNE, cDE, cSE, cInE, b_c2t, X, Wacc);
    hipLaunchKernelGGL(drug_fin_k, dim3(B_), dim3(256), 0, stream, Wacc, U, cSE, b_c2t, X, 256);

    // 4 res-blocks:
    //   g (X->U, + Wacc epilogue), fused agg+l (U -> X, resid X, relu)
    for (int it = 0; it < 4; ++it) {
        hipMemsetAsync(Wacc, 0, B_ * 256 * sizeof(float), stream);
        gemm_n256(X, 256, WT_rtg, (const u16*)nullptr, U, 0, cInFO, Wacc, stream);
        {
            dim3 g(N2_ / 64), b(256);
            hipLaunchKernelGGL((gemm_aggl_k<8>), g, b, 0, stream,
                               U, WT_rtl, cPO, cNO, cDO, cSO, Wacc, b_rt_g, X, X);
        }
    }

    hipLaunchKernelGGL(x2g_bf2_k, dim3(B_), dim3(256), 0, stream, X, x2g, dafter);

    // ---------- heads (split-K fp32) ----------
    gemm_sk(x2g, W_fg1t, b_fg1t, t1t, skbuf, B_, 1024, 256, 8, 1, stream);
    gemm_sk(t1t, W_fg2t, b_fg2t, x2v, skbuf, B_, 256, 1024, 16, 0, stream);
    hipLaunchKernelGGL(build_xc_k, dim3(B_ * 512 / 256), dim3(256), 0, stream, dafter, x_chg, x2v, xc);
    gemm_sk(xc, W_fc1, b_fc1, f1, skbuf, B_, 1024, 512, 8, 1, stream);
    gemm_sk(f1, W_fc2, b_fc2, f2, skbuf, B_, 512, 1024, 16, 1, stream);
    hipLaunchKernelGGL(out_k, dim3(B_), dim3(64), 0, stream, f2, W_out, b_out, out);
}

// Round 14
// 1105.021 us; speedup vs baseline: 1.0158x; 1.0158x over previous
//
#include <hip/hip_runtime.h>
#include <cstdio>

// ---- problem constants (fixed by setup_inputs) ----
#define B_   256
#define L_   512
#define A_   40
#define FD_  78
#define FT_  54
#define LD_  128
#define P_   513            // L+1
#define ND_  (B_*A_)        // 10240 drug nodes
#define N2_  (B_*P_)        // 131328 protein nodes (= 1026*128, %128==0)
#define EB_  2046           // protein edges per batch: 2*(L-1)+2*L

typedef __attribute__((ext_vector_type(8))) short short8;
typedef __attribute__((ext_vector_type(4))) float floatx4;
typedef unsigned short u16;

__device__ __forceinline__ short f2bf(float f) {
    union { float f; unsigned u; } v; v.f = f;
    unsigned u = v.u;
    u += 0x7fff + ((u >> 16) & 1);   // round-to-nearest-even
    return (short)(u >> 16);
}
__device__ __forceinline__ float bf2f(u16 s) {
    union { unsigned u; float f; } v; v.u = ((unsigned)s) << 16; return v.f;
}

#define TBK 32
#define LDK 40   // LDS row stride in shorts: 80B (16B-aligned; 2-way bank alias free)
#define CSP 260  // fp32 epilogue-staging row stride (floats)

// LDS-only barrier: waits LDS ops, does NOT drain vmcnt -> global loads
// stay in flight across the barrier.  Correctness-verified rounds 6-12.
#define SYNC_LDS asm volatile("s_waitcnt lgkmcnt(0)\n\ts_barrier" ::: "memory")

// =====================================================================
// FUSED DRUG BRANCH (round-10/12 verified config: 512 threads, DR=20).
// Row-split: thread (half, col) computes 20 of the 40 rows of column
// col (acc[20]) -> 8 waves/block = 2 waves/SIMD.  r0 in {0,20} keeps
// the 20-float LDS reads 80B-aligned -> ds_read_b128 x5 (DR=10 broke
// alignment and doubled LDS instruction count: 218us vs 162us).
// Aggregation boundary (rows 19<->20) exchanged pre-agg via LDS.
// =====================================================================
#define DR_ 20
__global__ __launch_bounds__(512) void drug_fused_k(
    const float* __restrict__ drug_x,
    const float* __restrict__ W_c1d, const float* __restrict__ b_c1d,
    const float* __restrict__ W_c2d, const float* __restrict__ b_c2d,
    const float* __restrict__ W_rd_g, const float* __restrict__ b_rd_g,
    const float* __restrict__ W_rd_l,
    float* __restrict__ xg)
{
    __shared__ float Xb[2][156 * 40];      // 49.9 KB ping-pong, XT[k][r]
    __shared__ float bndA[256];            // pre-agg acc at row 19 (half 0)
    __shared__ float bndB[256];            // pre-agg acc at row 20 (half 1)
    const int b = blockIdx.x, t = threadIdx.x;
    const int col = t & 255, half = t >> 8;
    const int r0 = half * DR_;
    const float DI2 = 0.70710678118654752f;
    const float DI3 = 0.57735026918962576f;

    // stage drug_x[b] ([40][78] row-major) -> Xb[0] transposed
    for (int idx = t; idx < 40 * 78; idx += 512) {
        int r = idx / 78, k = idx - r * 78;
        Xb[0][k * 40 + r] = drug_x[(size_t)(b * A_ + r) * FD_ + k];
    }
    __syncthreads();

    float acc[DR_], hn[DR_];

    // acc[r] = sum_k XT[src][k][r0+r] * W[k][col]
    auto gemm_cols = [&](const float* __restrict__ Wp, int K, int N, int SRC) {
#pragma unroll
        for (int r = 0; r < DR_; ++r) acc[r] = 0.f;
        if (col < N) {
            for (int k = 0; k < K; ++k) {
                float w = Wp[(size_t)k * N + col];
                const float* xp = &Xb[SRC][k * 40 + r0];
#pragma unroll
                for (int r = 0; r < DR_; ++r)
                    acc[r] = fmaf(xp[r], w, acc[r]);
            }
        }
    };

    // graph agg (+bias, relu) with cross-half boundary exchange; store DST
    auto agg_store = [&](const float* __restrict__ bias, int N, int DST) {
        if (col < N) {
            if (half == 0) bndA[col] = acc[DR_ - 1];   // row 19
            else           bndB[col] = acc[0];         // row 20
        }
        __syncthreads();
        if (col < N) {
            float bi = bias[col];
#pragma unroll
            for (int r = 0; r < DR_; ++r) {
                int gr = r0 + r;
                float da = (gr == 0 || gr == A_ - 1) ? DI2 : DI3;
                float v = da * da * acc[r] + bi;
                if (gr > 0) {
                    float pv = (r > 0) ? acc[r - 1] : bndA[col];
                    v += ((gr - 1 == 0) ? DI2 : DI3) * da * pv;
                }
                if (gr < A_ - 1) {
                    float nv = (r < DR_ - 1) ? acc[r + 1] : bndB[col];
                    v += ((gr + 1 == A_ - 1) ? DI2 : DI3) * da * nv;
                }
                hn[r] = fmaxf(v, 0.f);
            }
#pragma unroll
            for (int r = 0; r < DR_; ++r) Xb[DST][col * 40 + r0 + r] = hn[r];
        }
        __syncthreads();
    };

    // conv1: 78 -> 78   (Xb0 -> Xb1)
    gemm_cols(W_c1d, FD_, FD_, 0);
    agg_store(b_c1d, FD_, 1);
    // conv2: 78 -> 156  (Xb1 -> Xb0)
    gemm_cols(W_c2d, FD_, 2 * FD_, 1);
    agg_store(b_c2d, 2 * FD_, 0);

    // 4 res-blocks
    for (int it = 0; it < 4; ++it) {
        gemm_cols(W_rd_g, 2 * FD_, 2 * FD_, 0);
        agg_store(b_rd_g, 2 * FD_, 1);
        gemm_cols(W_rd_l, 2 * FD_, 2 * FD_, 1);
        if (col < 2 * FD_) {
#pragma unroll
            for (int r = 0; r < DR_; ++r)
                hn[r] = fmaxf(acc[r] + Xb[0][col * 40 + r0 + r], 0.f);
        }
        __syncthreads();           // all reads of Xb0/Xb1 done
        if (col < 2 * FD_) {
#pragma unroll
            for (int r = 0; r < DR_; ++r) Xb[0][col * 40 + r0 + r] = hn[r];
        }
        __syncthreads();
    }

    // max-pool over 40 nodes (hn holds this thread's final rows)
    if (col < 2 * FD_) {
        float m = -INFINITY;
#pragma unroll
        for (int r = 0; r < DR_; ++r) m = fmaxf(m, hn[r]);
        if (half == 0) bndA[col] = m; else bndB[col] = m;
    }
    __syncthreads();
    if (half == 0 && col < 2 * FD_)
        xg[(size_t)b * (2 * FD_) + col] = fmaxf(bndA[col], bndB[col]);
}

// =====================================================================
// MFMA GEMM (fp32 A): C_fp32 = A[M,K]fp32 @ W (WT[N][Kp] bf16). For attention.
// =====================================================================
__global__ __launch_bounds__(256) void gemm_mfma_k(
    const float* __restrict__ A, const short* __restrict__ WT,
    float* __restrict__ C, int M, int N, int K, int Kp)
{
    __shared__ short As[128 * LDK];
    __shared__ short Bs[128 * LDK];
    const int bm = blockIdx.y * 128;
    const int bn = blockIdx.x * 128;
    const int tid  = threadIdx.x;
    const int wave = tid >> 6, lane = tid & 63;
    const int wm = (wave >> 1) * 64, wn = (wave & 1) * 64;
    const int lrow = lane & 15, quad = lane >> 4;

    floatx4 acc[4][4] = {};

    for (int k0 = 0; k0 < Kp; k0 += TBK) {
#pragma unroll
        for (int it = 0; it < 2; ++it) {
            int g   = it * 256 + tid;
            int row = g >> 2, kg = g & 3;
            int kb  = k0 + kg * 8;
            const float* arow = A + (size_t)(bm + row) * K + kb;
            short8 av;
#pragma unroll
            for (int j = 0; j < 8; ++j) av[j] = (kb + j < K) ? f2bf(arow[j]) : (short)0;
            *(short8*)&As[row * LDK + kg * 8] = av;
            *(short8*)&Bs[row * LDK + kg * 8] = *(const short8*)(WT + (size_t)(bn + row) * Kp + kb);
        }
        __syncthreads();
        short8 af[4], bfv[4];
#pragma unroll
        for (int i = 0; i < 4; ++i)
            af[i] = *(short8*)&As[(wm + i * 16 + lrow) * LDK + quad * 8];
#pragma unroll
        for (int j = 0; j < 4; ++j)
            bfv[j] = *(short8*)&Bs[(wn + j * 16 + lrow) * LDK + quad * 8];
#pragma unroll
        for (int i = 0; i < 4; ++i)
#pragma unroll
            for (int j = 0; j < 4; ++j)
                acc[i][j] = __builtin_amdgcn_mfma_f32_16x16x32_bf16(af[i], bfv[j], acc[i][j], 0, 0, 0);
        __syncthreads();
    }
#pragma unroll
    for (int i = 0; i < 4; ++i) {
        int grow0 = bm + wm + i * 16 + quad * 4;
#pragma unroll
        for (int j = 0; j < 4; ++j) {
            int col = bn + wn + j * 16 + lrow;
            size_t base = (size_t)grow0 * N + col;
#pragma unroll
            for (int r = 0; r < 4; ++r)
                C[base + (size_t)r * N] = acc[i][j][r];
        }
    }
}

// =====================================================================
// MFMA GEMM (bf16 A), 128x128 tile. For conv1 (N=128, K small).
// =====================================================================
__global__ __launch_bounds__(256) void gemm_bb_k(
    const u16* __restrict__ A, int lda, const short* __restrict__ WT, int Kp,
    const u16* __restrict__ resid, u16* __restrict__ C, int N, int act)
{
    __shared__ short As[128 * LDK];
    __shared__ short Bs[128 * LDK];
    const int bm = blockIdx.y * 128;
    const int bn = blockIdx.x * 128;
    const int tid  = threadIdx.x;
    const int wave = tid >> 6, lane = tid & 63;
    const int wm = (wave >> 1) * 64, wn = (wave & 1) * 64;
    const int lrow = lane & 15, quad = lane >> 4;

    floatx4 acc[4][4] = {};

    for (int k0 = 0; k0 < Kp; k0 += TBK) {
#pragma unroll
        for (int it = 0; it < 2; ++it) {
            int g   = it * 256 + tid;
            int row = g >> 2, kg = g & 3;
            int kb  = k0 + kg * 8;
            *(short8*)&As[row * LDK + kg * 8] = *(const short8*)(A + (size_t)(bm + row) * lda + kb);
            *(short8*)&Bs[row * LDK + kg * 8] = *(const short8*)(WT + (size_t)(bn + row) * Kp + kb);
        }
        __syncthreads();
        short8 af[4], bfv[4];
#pragma unroll
        for (int i = 0; i < 4; ++i)
            af[i] = *(short8*)&As[(wm + i * 16 + lrow) * LDK + quad * 8];
#pragma unroll
        for (int j = 0; j < 4; ++j)
            bfv[j] = *(short8*)&Bs[(wn + j * 16 + lrow) * LDK + quad * 8];
#pragma unroll
        for (int i = 0; i < 4; ++i)
#pragma unroll
            for (int j = 0; j < 4; ++j)
                acc[i][j] = __builtin_amdgcn_mfma_f32_16x16x32_bf16(af[i], bfv[j], acc[i][j], 0, 0, 0);
        __syncthreads();
    }
#pragma unroll
    for (int i = 0; i < 4; ++i) {
        int grow0 = bm + wm + i * 16 + quad * 4;
#pragma unroll
        for (int j = 0; j < 4; ++j) {
            int col = bn + wn + j * 16 + lrow;
            size_t base = (size_t)grow0 * N + col;
#pragma unroll
            for (int r = 0; r < 4; ++r) {
                float v = acc[i][j][r];
                size_t idx = base + (size_t)r * N;
                if (resid) v += bf2f(resid[idx]);
                if (act)   v = fmaxf(v, 0.f);
                C[idx] = (u16)f2bf(v);
            }
        }
    }
}

// =====================================================================
// MFMA GEMM, 64x256 tile, N=256, K = KT*32.  Round-7/8/12 verified:
// direct-B fragments + SYNC_LDS barriers + staged coalesced epilogue.
// launch_bounds (256,2): (256,3) tested round-13, neutral-to-negative.
// Optional Wacc epilogue (drug-row partial sums).
// =====================================================================
template<int KT>
__global__ __launch_bounds__(256, 2) void gemm_n256pw_k(
    const u16* __restrict__ A, const short* __restrict__ WT,
    const u16* __restrict__ resid, u16* __restrict__ C, int act,
    const float* __restrict__ cInF, float* __restrict__ Wacc)
{
    constexpr int K = KT * TBK;
    __shared__ short As[64 * LDK];      // 5 KB
    __shared__ float Cs[16 * CSP];      // 16.25 KB epilogue staging
    const int bm = blockIdx.x * 64;
    const int tid  = threadIdx.x;
    const int wave = tid >> 6, lane = tid & 63;
    const int wn = wave * 64;
    const int lrow = lane & 15, quad = lane >> 4;
    const int srow = tid >> 2, skg = tid & 3;   // staging row / k-group

    floatx4 acc[4][4] = {};

    short8 aR[KT];
#pragma unroll
    for (int kt = 0; kt < KT; ++kt)
        aR[kt] = *(const short8*)(A + (size_t)(bm + srow) * K + kt * TBK + skg * 8);

    const short* bp0 = WT + (size_t)(wn +  0 + lrow) * K + quad * 8;
    const short* bp1 = WT + (size_t)(wn + 16 + lrow) * K + quad * 8;
    const short* bp2 = WT + (size_t)(wn + 32 + lrow) * K + quad * 8;
    const short* bp3 = WT + (size_t)(wn + 48 + lrow) * K + quad * 8;
    short8 bfv[2][4];
    bfv[0][0] = *(const short8*)bp0;
    bfv[0][1] = *(const short8*)bp1;
    bfv[0][2] = *(const short8*)bp2;
    bfv[0][3] = *(const short8*)bp3;

#pragma unroll
    for (int kt = 0; kt < KT; ++kt) {
        const int cur = kt & 1, nxt = cur ^ 1;
        *(short8*)&As[srow * LDK + skg * 8] = aR[kt];
        SYNC_LDS;
        if (kt + 1 < KT) {
            const int kn = (kt + 1) * TBK;
            bfv[nxt][0] = *(const short8*)(bp0 + kn);
            bfv[nxt][1] = *(const short8*)(bp1 + kn);
            bfv[nxt][2] = *(const short8*)(bp2 + kn);
            bfv[nxt][3] = *(const short8*)(bp3 + kn);
        }
        short8 af[4];
#pragma unroll
        for (int i = 0; i < 4; ++i)
            af[i] = *(short8*)&As[(i * 16 + lrow) * LDK + quad * 8];
#pragma unroll
        for (int i = 0; i < 4; ++i)
#pragma unroll
            for (int j = 0; j < 4; ++j)
                acc[i][j] = __builtin_amdgcn_mfma_f32_16x16x32_bf16(af[i], bfv[cur][j], acc[i][j], 0, 0, 0);
        SYNC_LDS;
    }

    if (cInF) {
        const int b0 = bm / P_;
        const int b1 = (bm + 63) / P_;
        float s0[4] = {0.f, 0.f, 0.f, 0.f};
        float s1[4] = {0.f, 0.f, 0.f, 0.f};
#pragma unroll
        for (int i = 0; i < 4; ++i) {
#pragma unroll
            for (int r = 0; r < 4; ++r) {
                int grow = bm + i * 16 + quad * 4 + r;
                float ci = cInF[grow];
                bool hi = (grow / P_) != b0;
#pragma unroll
                for (int j = 0; j < 4; ++j) {
                    float v = ci * acc[i][j][r];
                    if (hi) s1[j] += v; else s0[j] += v;
                }
            }
        }
#pragma unroll
        for (int j = 0; j < 4; ++j) {
            s0[j] += __shfl_xor(s0[j], 16);
            s0[j] += __shfl_xor(s0[j], 32);
            s1[j] += __shfl_xor(s1[j], 16);
            s1[j] += __shfl_xor(s1[j], 32);
        }
        if (quad == 0) {
#pragma unroll
            for (int j = 0; j < 4; ++j) {
                int col = wn + j * 16 + lrow;
                atomicAdd(&Wacc[(size_t)b0 * 256 + col], s0[j]);
                if (b1 != b0) atomicAdd(&Wacc[(size_t)b1 * 256 + col], s1[j]);
            }
        }
    }

    // staged C epilogue: fp32 LDS re-layout -> coalesced short8 IO
    const int erl = tid >> 4;
    const int ecc = (tid & 15) * 16;
#pragma unroll
    for (int i = 0; i < 4; ++i) {
#pragma unroll
        for (int j = 0; j < 4; ++j)
#pragma unroll
            for (int r = 0; r < 4; ++r)
                Cs[(quad * 4 + r) * CSP + wn + j * 16 + lrow] = acc[i][j][r];
        SYNC_LDS;
        const int grow = bm + i * 16 + erl;
        const size_t gbase = (size_t)grow * 256 + ecc;
#pragma unroll
        for (int h = 0; h < 2; ++h) {
            const float* cp = &Cs[erl * CSP + ecc + h * 8];
            short8 ov;
            if (resid) {
                short8 rv = *(const short8*)(resid + gbase + h * 8);
#pragma unroll
                for (int e = 0; e < 8; ++e) {
                    float v = cp[e] + bf2f((u16)rv[e]);
                    if (act) v = fmaxf(v, 0.f);
                    ov[e] = f2bf(v);
                }
            } else {
#pragma unroll
                for (int e = 0; e < 8; ++e) {
                    float v = cp[e];
                    if (act) v = fmaxf(v, 0.f);
                    ov[e] = f2bf(v);
                }
            }
            *(short8*)(C + gbase + h * 8) = ov;
        }
        SYNC_LDS;
    }
}

// =====================================================================
// Fused aggregation + l-GEMM (round-7/8/12 verified).
// =====================================================================
template<int KT>
__global__ __launch_bounds__(256, 2) void gemm_aggl_k(
    const u16* __restrict__ U, const short* __restrict__ WT,
    const float* __restrict__ cPc, const float* __restrict__ cNc,
    const float* __restrict__ cDc, const float* __restrict__ cSc,
    const float* __restrict__ Wacc, const float* __restrict__ bias,
    const u16* __restrict__ resid, u16* __restrict__ C)
{
    constexpr int K = KT * TBK;
    __shared__ short As[64 * LDK];      // 5 KB
    __shared__ float Cs[16 * CSP];      // 16.25 KB epilogue staging
    const int bm = blockIdx.x * 64;
    const int tid  = threadIdx.x;
    const int wave = tid >> 6, lane = tid & 63;
    const int wn = wave * 64;
    const int lrow = lane & 15, quad = lane >> 4;
    const int srow = tid >> 2, skg = tid & 3;

    const int r    = bm + srow;
    const int bl   = r / P_;
    const int irow = r - bl * P_;
    const bool isD = (irow == L_);
    const size_t rD = (size_t)bl * P_ + L_;
    const int rm = (r == 0) ? 0 : r - 1;            // cP==0 at i==0
    const int rp = (r == N2_ - 1) ? r : r + 1;      // cN==0 at i==L-1
    const float cs = cSc[r];
    const float cp = isD ? 0.f : cPc[r];
    const float cn = isD ? 0.f : cNc[r];
    const float cd = isD ? 0.f : cDc[r];
    const float* wrow = Wacc + (size_t)bl * 256;

    floatx4 acc[4][4] = {};

    const u16* uSp = U + (size_t)r  * K + skg * 8;
    const u16* uMp = U + (size_t)rm * K + skg * 8;
    const u16* uPp = U + (size_t)rp * K + skg * 8;
    const u16* uDp = U + rD * K + skg * 8;

    short8 uS[KT];
#pragma unroll
    for (int kt = 0; kt < KT; ++kt) uS[kt] = *(const short8*)(uSp + kt * TBK);
    short8 uM = *(const short8*)uMp;
    short8 uP = *(const short8*)uPp;
    short8 uD = *(const short8*)uDp;

    const short* bp0 = WT + (size_t)(wn +  0 + lrow) * K + quad * 8;
    const short* bp1 = WT + (size_t)(wn + 16 + lrow) * K + quad * 8;
    const short* bp2 = WT + (size_t)(wn + 32 + lrow) * K + quad * 8;
    const short* bp3 = WT + (size_t)(wn + 48 + lrow) * K + quad * 8;

#pragma unroll
    for (int kt = 0; kt < KT; ++kt) {
        const int kb = kt * TBK + skg * 8;
        float4 bi0 = *(const float4*)(bias + kb);
        float4 bi1 = *(const float4*)(bias + kb + 4);
        float bv[8] = {bi0.x, bi0.y, bi0.z, bi0.w, bi1.x, bi1.y, bi1.z, bi1.w};
        if (isD) {
            float4 w0 = *(const float4*)(wrow + kb);
            float4 w1 = *(const float4*)(wrow + kb + 4);
            bv[0] += w0.x; bv[1] += w0.y; bv[2] += w0.z; bv[3] += w0.w;
            bv[4] += w1.x; bv[5] += w1.y; bv[6] += w1.z; bv[7] += w1.w;
        }
        short8 av;
#pragma unroll
        for (int e = 0; e < 8; ++e) {
            float v = cs * bf2f((u16)uS[kt][e]) + cp * bf2f((u16)uM[e])
                    + cn * bf2f((u16)uP[e]) + cd * bf2f((u16)uD[e]) + bv[e];
            av[e] = f2bf(fmaxf(v, 0.f));
        }
        *(short8*)&As[srow * LDK + skg * 8] = av;
        const int kc = kt * TBK;
        short8 bfv0 = *(const short8*)(bp0 + kc);
        short8 bfv1 = *(const short8*)(bp1 + kc);
        short8 bfv2 = *(const short8*)(bp2 + kc);
        short8 bfv3 = *(const short8*)(bp3 + kc);
        SYNC_LDS;
        if (kt + 1 < KT) {
            const int kn = (kt + 1) * TBK;
            uM = *(const short8*)(uMp + kn);
            uP = *(const short8*)(uPp + kn);
            uD = *(const short8*)(uDp + kn);
        }
        short8 af[4];
#pragma unroll
        for (int i = 0; i < 4; ++i)
            af[i] = *(short8*)&As[(i * 16 + lrow) * LDK + quad * 8];
#pragma unroll
        for (int i = 0; i < 4; ++i) {
            acc[i][0] = __builtin_amdgcn_mfma_f32_16x16x32_bf16(af[i], bfv0, acc[i][0], 0, 0, 0);
            acc[i][1] = __builtin_amdgcn_mfma_f32_16x16x32_bf16(af[i], bfv1, acc[i][1], 0, 0, 0);
            acc[i][2] = __builtin_amdgcn_mfma_f32_16x16x32_bf16(af[i], bfv2, acc[i][2], 0, 0, 0);
            acc[i][3] = __builtin_amdgcn_mfma_f32_16x16x32_bf16(af[i], bfv3, acc[i][3], 0, 0, 0);
        }
        SYNC_LDS;
    }

    const int erl = tid >> 4;
    const int ecc = (tid & 15) * 16;
#pragma unroll
    for (int i = 0; i < 4; ++i) {
#pragma unroll
        for (int j = 0; j < 4; ++j)
#pragma unroll
            for (int r2 = 0; r2 < 4; ++r2)
                Cs[(quad * 4 + r2) * CSP + wn + j * 16 + lrow] = acc[i][j][r2];
        SYNC_LDS;
        const int grow = bm + i * 16 + erl;
        const size_t gbase = (size_t)grow * 256 + ecc;
#pragma unroll
        for (int h = 0; h < 2; ++h) {
            const float* cp2 = &Cs[erl * CSP + ecc + h * 8];
            short8 rv = *(const short8*)(resid + gbase + h * 8);
            short8 ov;
#pragma unroll
            for (int e = 0; e < 8; ++e) {
                float v = cp2[e] + bf2f((u16)rv[e]);
                ov[e] = f2bf(fmaxf(v, 0.f));
            }
            *(short8*)(C + gbase + h * 8) = ov;
        }
        SYNC_LDS;
    }
}

static inline void gemm_n256(const u16* A, int K, const short* WT,
                             const u16* resid, u16* C, int act,
                             const float* cInF, float* Wacc, hipStream_t s)
{
    dim3 g(N2_ / 64), b(256);
    if (K == 128)
        hipLaunchKernelGGL((gemm_n256pw_k<4>), g, b, 0, s, A, WT, resid, C, act, cInF, Wacc);
    else
        hipLaunchKernelGGL((gemm_n256pw_k<8>), g, b, 0, s, A, WT, resid, C, act, cInF, Wacc);
}

// one-time weight transpose+cast: WT[n*Kp+k] = bf16(W[k*Nreal+n]), zero padded
__global__ void wt_cvt_k(const float* __restrict__ W, short* __restrict__ WT,
                         int K, int Nreal, int Kp, int Ntot)
{
    int idx = blockIdx.x * 256 + threadIdx.x;
    if (idx >= Ntot * Kp) return;
    int n = idx / Kp, k = idx - n * Kp;
    WT[idx] = (k < K && n < Nreal) ? f2bf(W[(size_t)k * Nreal + n]) : (short)0;
}

// =====================================================================
// Split-K fp32 GEMM for small-M (M=256) head GEMMs.
// =====================================================================
#define BM 64
#define BN 64
#define BKK 16
__global__ __launch_bounds__(256) void gemm_skA_k(
    const float* __restrict__ Amat, const float* __restrict__ Wmat,
    float* __restrict__ part, int M, int N, int K, int Kc)
{
    __shared__ float As[BKK][BM + 4];
    __shared__ float Ws[BKK][BN];
    const int bm = blockIdx.y * BM;
    const int bn = blockIdx.x * BN;
    const int sk = blockIdx.z;
    const int kb0  = sk * Kc;
    const int kend = min(K, kb0 + Kc);
    const int tx = threadIdx.x, ty = threadIdx.y;
    const int tid = ty * 16 + tx;
    float acc[4][4] = {};

    for (int k0 = kb0; k0 < kend; k0 += BKK) {
#pragma unroll
        for (int j = 0; j < 4; ++j) {
            int l = tid + 256 * j;
            int m = l >> 4, kk = l & 15;
            int gm = bm + m, gk = k0 + kk;
            As[kk][m] = (gm < M && gk < kend) ? Amat[(size_t)gm * K + gk] : 0.f;
        }
#pragma unroll
        for (int j = 0; j < 4; ++j) {
            int l = tid + 256 * j;
            int kk = l >> 6, n = l & 63;
            int gk = k0 + kk, gn = bn + n;
            Ws[kk][n] = (gk < kend && gn < N) ? Wmat[(size_t)gk * N + gn] : 0.f;
        }
        __syncthreads();
#pragma unroll
        for (int k = 0; k < BKK; ++k) {
            float4 a4 = *(const float4*)&As[k][ty * 4];
            float4 w4 = *(const float4*)&Ws[k][tx * 4];
            float av[4] = {a4.x, a4.y, a4.z, a4.w};
            float wv[4] = {w4.x, w4.y, w4.z, w4.w};
#pragma unroll
            for (int i = 0; i < 4; ++i)
#pragma unroll
                for (int j = 0; j < 4; ++j)
                    acc[i][j] = fmaf(av[i], wv[j], acc[i][j]);
        }
        __syncthreads();
    }
#pragma unroll
    for (int i = 0; i < 4; ++i) {
        int gm = bm + ty * 4 + i;
        if (gm >= M) continue;
#pragma unroll
        for (int j = 0; j < 4; ++j) {
            int gn = bn + tx * 4 + j;
            if (gn >= N) continue;
            part[((size_t)sk * M + gm) * N + gn] = acc[i][j];
        }
    }
}

__global__ void gemm_skB_k(const float* __restrict__ part, const float* __restrict__ bias,
                           float* __restrict__ C, int M, int N, int SK, int act)
{
    int idx = blockIdx.x * 256 + threadIdx.x;
    if (idx >= M * N) return;
    int n = idx % N;
    float v = bias ? bias[n] : 0.f;
    for (int s = 0; s < SK; ++s) v += part[(size_t)s * M * N + idx];
    if (act) v = fmaxf(v, 0.f);
    C[idx] = v;
}

static inline void gemm_sk(const float* A, const float* W, const float* bias,
                           float* C, float* skbuf, int M, int N, int K, int SK, int act,
                           hipStream_t s)
{
    int Kc = (K + SK - 1) / SK;
    dim3 g((N + 63) / 64, (M + 63) / 64, SK), b(16, 16);
    hipLaunchKernelGGL(gemm_skA_k, g, b, 0, s, A, W, skbuf, M, N, K, Kc);
    hipLaunchKernelGGL(gemm_skB_k, dim3((M * N + 255) / 256), dim3(256), 0, s,
                       skbuf, bias, C, M, N, SK, act);
}

// =====================================================================
// Attention epilogue + softmax
// =====================================================================
__global__ __launch_bounds__(256) void att_dot_k(
    const float* __restrict__ Hs, const float* __restrict__ b1,
    const float* __restrict__ W2, const float* __restrict__ b2,
    float* __restrict__ scores)
{
    int w = threadIdx.x >> 6, lane = threadIdx.x & 63;
    float b1v = (lane < FT_) ? b1[lane] : 0.f;
    float w2v = (lane < FT_) ? W2[lane] : 0.f;
    float b2v = b2[0];
    int base = blockIdx.x * 64 + w * 16;
    for (int rr = 0; rr < 16; ++rr) {
        int r = base + rr;
        float v = 0.f;
        if (lane < FT_) v = tanhf(Hs[(size_t)r * 128 + lane] + b1v) * w2v;
#pragma unroll
        for (int o = 32; o; o >>= 1) v += __shfl_down(v, o);
        if (lane == 0) {
            int bl = r / P_, i = r - bl * P_;
            if (i < L_) scores[bl * L_ + i] = v + b2v;
        }
    }
}

__global__ __launch_bounds__(512) void softmax_k(
    const float* __restrict__ scores, float* __restrict__ att, float* __restrict__ attsum)
{
    int b = blockIdx.x, t = threadIdx.x;
    __shared__ float sm[8];
    __shared__ float bcast;
    float v = scores[b * L_ + t];
    float m = v;
#pragma unroll
    for (int o = 32; o; o >>= 1) m = fmaxf(m, __shfl_down(m, o));
    if ((t & 63) == 0) sm[t >> 6] = m;
    __syncthreads();
    if (t == 0) { float mm = sm[0]; for (int i = 1; i < 8; ++i) mm = fmaxf(mm, sm[i]); bcast = mm; }
    __syncthreads();
    float mx = bcast;
    float e = expf(v - mx);
    float s = e;
#pragma unroll
    for (int o = 32; o; o >>= 1) s += __shfl_down(s, o);
    __syncthreads();
    if ((t & 63) == 0) sm[t >> 6] = s;
    __syncthreads();
    if (t == 0) { float ss = 0; for (int i = 0; i < 8; ++i) ss += sm[i]; bcast = ss; }
    __syncthreads();
    float a = e / bcast;
    att[b * L_ + t] = a;
    float s2 = a;
#pragma unroll
    for (int o = 32; o; o >>= 1) s2 += __shfl_down(s2, o);
    __syncthreads();
    if ((t & 63) == 0) sm[t >> 6] = s2;
    __syncthreads();
    if (t == 0) { float ss = 0; for (int i = 0; i < 8; ++i) ss += sm[i]; attsum[b] = ss; }
}

// =====================================================================
// Protein GCN coefficients
// =====================================================================
__global__ void coef_deg_k(const float* __restrict__ prot_ea, const float* __restrict__ att,
                           const float* __restrict__ attsum, float* __restrict__ dinv, int use_ea)
{
    int r = blockIdx.x * 256 + threadIdx.x;
    if (r >= N2_) return;
    int b = r / P_, i = r - b * P_;
    float deg;
    if (i == L_) {
        deg = 1.f + (use_ea ? attsum[b] : (float)L_);
    } else {
        float wP = (i >= 1)      ? (use_ea ? prot_ea[b * EB_ + (i - 1)]   : 1.f) : 0.f;
        float wN = (i <= L_ - 2) ? (use_ea ? prot_ea[b * EB_ + 511 + i]   : 1.f) : 0.f;
        float wD = use_ea ? att[b * L_ + i] : 1.f;
        deg = 1.f + wP + wN + wD;
    }
    dinv[r] = rsqrtf(deg);
}

__global__ void coef_k(const float* __restrict__ dinv, const float* __restrict__ prot_ea,
                       const float* __restrict__ att, float* __restrict__ cP, float* __restrict__ cN,
                       float* __restrict__ cD, float* __restrict__ cS, float* __restrict__ cIn,
                       float* __restrict__ cInF, int use_ea)
{
    int r = blockIdx.x * 256 + threadIdx.x;
    if (r >= N2_) return;
    int b = r / P_, i = r - b * P_;
    float di = dinv[r];
    cS[r] = di * di;
    if (i == L_) { cP[r] = 0.f; cN[r] = 0.f; cD[r] = 0.f; cInF[r] = 0.f; return; }
    float wP = (i >= 1)      ? (use_ea ? prot_ea[b * EB_ + (i - 1)] : 1.f) : 0.f;
    float wN = (i <= L_ - 2) ? (use_ea ? prot_ea[b * EB_ + 511 + i] : 1.f) : 0.f;
    float wD = use_ea ? att[b * L_ + i] : 1.f;
    float dD = dinv[b * P_ + L_];
    cP[r] = (i >= 1)      ? dinv[r - 1] * wP * di : 0.f;
    cN[r] = (i <= L_ - 2) ? dinv[r + 1] * wN * di : 0.f;
    cD[r] = dD * wD * di;
    float ci = di * wD * dD;
    cIn[b * L_ + i] = ci;
    cInF[r] = ci;
}

// =====================================================================
// Vectorized protein aggregation (bf16 in/out, fp32 math), short8 loads.
// (used for conv1/conv2 aggregation)
// =====================================================================
template<int F>
__global__ __launch_bounds__(256) void prot_agg_res_k(
    const u16* __restrict__ h, const float* __restrict__ cP,
    const float* __restrict__ cN, const float* __restrict__ cD,
    const float* __restrict__ cS, const float* __restrict__ cIn,
    const float* __restrict__ bias, u16* __restrict__ outp,
    float* __restrict__ Wacc)
{
    constexpr int G = F / 8;
    constexpr int RPB = 256 / G;
    __shared__ float pacc[RPB * F];     // 8 KB
    int t = threadIdx.x;
    int rl = t / G, g = t - rl * G;
    int base = blockIdx.x * RPB;
    int r = base + rl;
    int bl = r / P_, i = r - bl * P_;
    int f0 = g * 8;
    const u16* hs = h + (size_t)r * F + f0;
    if (i == L_) {
#pragma unroll
        for (int e = 0; e < 8; ++e) pacc[rl * F + f0 + e] = 0.f;
    } else {
        const u16* hd = h + ((size_t)bl * P_ + L_) * F + f0;
        float cs = cS[r], cd = cD[r], cp = cP[r], cn = cN[r];
        float ci = cIn[bl * L_ + i];
        short8 vs = *(const short8*)hs;
        short8 vd = *(const short8*)hd;
        short8 vp = *(const short8*)(hs - (i > 0 ? F : 0));   // cp==0 at i==0
        short8 vn = *(const short8*)(hs + F);                  // cn==0 at i==L-1
        short8 ov;
#pragma unroll
        for (int e = 0; e < 8; ++e) {
            float hv = bf2f((u16)vs[e]);
            pacc[rl * F + f0 + e] = ci * hv;
            float v = cs * hv + cd * bf2f((u16)vd[e]) + bias[f0 + e];
            v += cp * bf2f((u16)vp[e]);
            v += cn * bf2f((u16)vn[e]);
            ov[e] = f2bf(fmaxf(v, 0.f));
        }
        *(short8*)(outp + (size_t)r * F + f0) = ov;
    }
    __syncthreads();
    int f = t;
    if (f < F) {
        int b0   = base / P_;
        int bend = (base + RPB - 1) / P_;
        float s0 = 0.f, s1 = 0.f;
#pragma unroll
        for (int rr = 0; rr < RPB; ++rr) {
            float v = pacc[rr * F + f];
            if ((base + rr) / P_ == b0) s0 += v; else s1 += v;
        }
        atomicAdd(&Wacc[(size_t)b0 * F + f], s0);
        if (bend != b0) atomicAdd(&Wacc[(size_t)bend * F + f], s1);
    }
}

// finalize drug rows: V[drug] = relu(Wacc + cS*h[drug] + bias)
__global__ void drug_fin_k(const float* __restrict__ Wacc, const u16* __restrict__ h,
                           const float* __restrict__ cS, const float* __restrict__ bias,
                           u16* __restrict__ outp, int F)
{
    int bl = blockIdx.x, t = threadIdx.x;
    if (t >= F) return;
    size_t rD = (size_t)bl * P_ + L_;
    float v = Wacc[(size_t)bl * F + t] + cS[rD] * bf2f(h[rD * F + t]) + bias[t];
    outp[rD * F + t] = (u16)f2bf(fmaxf(v, 0.f));
}

// build bf16 conv1 input: Xin[N2][64], cols<54 = prot_x (drug rows from t2d), else 0
__global__ void xin_k(const float* __restrict__ prot_x, const float* __restrict__ t2d,
                      u16* __restrict__ Xin)
{
    int idx = blockIdx.x * 256 + threadIdx.x;
    if (idx >= N2_ * 64) return;
    int r = idx >> 6, t = idx & 63;
    int bl = r / P_, i = r - bl * P_;
    float v = 0.f;
    if (t < FT_) v = (i == L_) ? t2d[bl * FT_ + t] : prot_x[(size_t)r * FT_ + t];
    Xin[idx] = (u16)f2bf(v);
}

// per-batch max over residues + drug row extraction (vectorized, F=256)
__global__ __launch_bounds__(256) void x2g_bf2_k(const u16* __restrict__ X,
                                                 float* __restrict__ x2g, float* __restrict__ da)
{
    __shared__ float red[2048];
    int t = threadIdx.x;
    int rl = t >> 5, g = t & 31;
    int bl = blockIdx.x, f0 = g * 8;
    const u16* xb = X + (size_t)bl * P_ * 256;
    float m[8];
#pragma unroll
    for (int e = 0; e < 8; ++e) m[e] = -INFINITY;
    for (int j = rl; j < L_; j += 8) {
        short8 v = *(const short8*)(xb + (size_t)j * 256 + f0);
#pragma unroll
        for (int e = 0; e < 8; ++e) m[e] = fmaxf(m[e], bf2f((u16)v[e]));
    }
#pragma unroll
    for (int e = 0; e < 8; ++e) red[rl * 256 + f0 + e] = m[e];
    __syncthreads();
    if (rl == 0) {
        short8 vd = *(const short8*)(xb + (size_t)L_ * 256 + f0);
#pragma unroll
        for (int e = 0; e < 8; ++e) {
            float v = red[f0 + e];
            for (int rr = 1; rr < 8; ++rr) v = fmaxf(v, red[rr * 256 + f0 + e]);
            x2g[bl * 256 + f0 + e] = v;
            da[bl * 256 + f0 + e] = bf2f((u16)vd[e]);
        }
    }
}

__global__ void build_xc_k(const float* __restrict__ da, const float* __restrict__ x_chg,
                           const float* __restrict__ x2v, float* __restrict__ xc)
{
    int idx = blockIdx.x * 256 + threadIdx.x;
    if (idx >= B_ * 512) return;
    int b = idx >> 9, c = idx & 511;
    float v = (c < 256) ? fmaxf(da[b * 256 + c], x_chg[b * 256 + c])
                        : x2v[b * 256 + (c - 256)];
    xc[idx] = v;
}

__global__ __launch_bounds__(64) void out_k(const float* __restrict__ f2,
                                            const float* __restrict__ W,
                                            const float* __restrict__ bias,
                                            float* __restrict__ out)
{
    int row = blockIdx.x, t = threadIdx.x;
    float v = 0.f;
    for (int k = t; k < 512; k += 64) v = fmaf(f2[(size_t)row * 512 + k], W[k], v);
#pragma unroll
    for (int o = 32; o; o >>= 1) v += __shfl_down(v, o);
    if (t == 0) out[row] = v + bias[0];
}

// =====================================================================
extern "C" void kernel_launch(void* const* d_in, const int* in_sizes, int n_in,
                              void* d_out, int out_size, void* d_ws, size_t ws_size,
                              hipStream_t stream)
{
    const float* drug_x  = (const float*)d_in[0];
    const float* prot_x  = (const float*)d_in[3];
    const float* prot_ea = (const float*)d_in[6];
    const float* W_c1d = (const float*)d_in[7];   const float* b_c1d = (const float*)d_in[8];
    const float* W_c2d = (const float*)d_in[9];   const float* b_c2d = (const float*)d_in[10];
    const float* W_rd_g = (const float*)d_in[11]; const float* b_rd_g = (const float*)d_in[12];
    const float* W_rd_l = (const float*)d_in[13];
    const float* W_fg1d = (const float*)d_in[14]; const float* b_fg1d = (const float*)d_in[15];
    const float* W_fg2d = (const float*)d_in[16]; const float* b_fg2d = (const float*)d_in[17];
    const float* W_fg3d = (const float*)d_in[18]; const float* b_fg3d = (const float*)d_in[19];
    const float* W_att1 = (const float*)d_in[20]; const float* b_att1 = (const float*)d_in[21];
    const float* W_att2 = (const float*)d_in[22]; const float* b_att2 = (const float*)d_in[23];
    const float* W_c1t = (const float*)d_in[24];  const float* b_c1t = (const float*)d_in[25];
    const float* W_c2t = (const float*)d_in[26];  const float* b_c2t = (const float*)d_in[27];
    const float* W_rt_g = (const float*)d_in[28]; const float* b_rt_g = (const float*)d_in[29];
    const float* W_rt_l = (const float*)d_in[30];
    const float* W_fg1t = (const float*)d_in[31]; const float* b_fg1t = (const float*)d_in[32];
    const float* W_fg2t = (const float*)d_in[33]; const float* b_fg2t = (const float*)d_in[34];
    const float* W_fc1 = (const float*)d_in[35];  const float* b_fc1 = (const float*)d_in[36];
    const float* W_fc2 = (const float*)d_in[37];  const float* b_fc2 = (const float*)d_in[38];
    const float* W_out = (const float*)d_in[39];  const float* b_out = (const float*)d_in[40];
    float* out = (float*)d_out;

    float* ws = (float*)d_ws;
    size_t off = 0;
    auto alloc = [&](size_t n) {
        n = (n + 3) & ~(size_t)3;          // 16B alignment
        float* p = ws + off; off += n; return p;
    };

    // big bf16 activation buffers (full batch, width up to 256): 67.2 MB each
    u16* U = (u16*)alloc((size_t)N2_ * 128);
    u16* V = (u16*)alloc((size_t)N2_ * 128);
    u16* X = (u16*)alloc((size_t)N2_ * 128);
    u16* Xin = (u16*)alloc((size_t)N2_ * 32);    // [N2][64] bf16
    float* Hs = (float*)U;                        // fp32 attention scratch aliases U
    float* Wacc = alloc(B_ * 256);                // drug-row partial sums (fp32)
    float* xg    = alloc(B_ * 156);
    float* t1d   = alloc(B_ * 1024);
    float* t2d   = alloc(B_ * FT_);
    float* x_chg = alloc(B_ * 256);
    float* scores = alloc(B_ * 512);
    float* att    = alloc(B_ * 512);
    float* attsum = alloc(B_);
    float* dinvE = alloc(N2_);
    float* cPE = alloc(N2_); float* cNE = alloc(N2_); float* cDE = alloc(N2_); float* cSE = alloc(N2_);
    float* cInE = alloc(B_ * 512);
    float* cInFE = alloc(N2_);
    float* dinvO = alloc(N2_);
    float* cPO = alloc(N2_); float* cNO = alloc(N2_); float* cDO = alloc(N2_); float* cSO = alloc(N2_);
    float* cInO = alloc(B_ * 512);
    float* cInFO = alloc(N2_);
    float* x2g = alloc(B_ * 256);
    float* dafter = alloc(B_ * 256);
    float* t1t = alloc(B_ * 1024);
    float* x2v = alloc(B_ * 256);
    float* xc  = alloc(B_ * 512);
    float* f1  = alloc(B_ * 1024);
    float* f2  = alloc(B_ * 512);
    float* skbuf = alloc((size_t)2 * 1024 * 1024);
    // bf16 transposed weights
    short* WT_c1t = (short*)alloc(128 * 64 / 2);
    short* WT_c2t = (short*)alloc(256 * 128 / 2);
    short* WT_rtg = (short*)alloc(256 * 256 / 2);
    short* WT_rtl = (short*)alloc(256 * 256 / 2);
    short* WT_att = (short*)alloc(128 * 64 / 2);

    if (off * sizeof(float) > ws_size) {
        fprintf(stderr, "kernel_launch: workspace too small: need %zu, have %zu\n",
                off * sizeof(float), ws_size);
        return;
    }

    // ---------- one-time weight cast/transpose ----------
    hipLaunchKernelGGL(wt_cvt_k, dim3((128 * 64 + 255) / 256), dim3(256), 0, stream,  W_c1t, WT_c1t, FT_, 128, 64, 128);
    hipLaunchKernelGGL(wt_cvt_k, dim3((256 * 128 + 255) / 256), dim3(256), 0, stream, W_c2t, WT_c2t, 128, 256, 128, 256);
    hipLaunchKernelGGL(wt_cvt_k, dim3((256 * 256 + 255) / 256), dim3(256), 0, stream, W_rt_g, WT_rtg, 256, 256, 256, 256);
    hipLaunchKernelGGL(wt_cvt_k, dim3((256 * 256 + 255) / 256), dim3(256), 0, stream, W_rt_l, WT_rtl, 256, 256, 256, 256);
    hipLaunchKernelGGL(wt_cvt_k, dim3((128 * 64 + 255) / 256), dim3(256), 0, stream,  W_att1, WT_att, FT_, FT_, 64, 128);

    // ---------- drug branch: ONE fused kernel (10 layers + max-pool) ----------
    hipLaunchKernelGGL(drug_fused_k, dim3(B_), dim3(512), 0, stream,
                       drug_x, W_c1d, b_c1d, W_c2d, b_c2d, W_rd_g, b_rd_g, W_rd_l, xg);
    gemm_sk(xg,  W_fg1d, b_fg1d, t1d,   skbuf, B_, 1024, 156, 4, 1, stream);
    gemm_sk(t1d, W_fg2d, b_fg2d, t2d,   skbuf, B_, FT_, 1024, 16, 0, stream);
    gemm_sk(t2d, W_fg3d, b_fg3d, x_chg, skbuf, B_, 2 * LD_, FT_, 2, 1, stream);

    // ---------- attention (MFMA) ----------
    {
        dim3 g(1, N2_ / 128), b(256);
        hipLaunchKernelGGL(gemm_mfma_k, g, b, 0, stream, prot_x, WT_att, Hs, N2_, 128, FT_, 64);
    }
    hipLaunchKernelGGL(att_dot_k, dim3(N2_ / 64), dim3(256), 0, stream, Hs, b_att1, W_att2, b_att2, scores);
    hipLaunchKernelGGL(softmax_k, dim3(B_), dim3(512), 0, stream, scores, att, attsum);

    // ---------- protein GCN coefficients ----------
    hipLaunchKernelGGL(coef_deg_k, dim3((N2_ + 255) / 256), dim3(256), 0, stream, prot_ea, att, attsum, dinvE, 1);
    hipLaunchKernelGGL(coef_k, dim3((N2_ + 255) / 256), dim3(256), 0, stream, dinvE, prot_ea, att, cPE, cNE, cDE, cSE, cInE, cInFE, 1);
    hipLaunchKernelGGL(coef_deg_k, dim3((N2_ + 255) / 256), dim3(256), 0, stream, prot_ea, att, attsum, dinvO, 0);
    hipLaunchKernelGGL(coef_k, dim3((N2_ + 255) / 256), dim3(256), 0, stream, dinvO, prot_ea, att, cPO, cNO, cDO, cSO, cInO, cInFO, 0);

    // ---------- protein branch (full batch, bf16 activations) ----------
    hipLaunchKernelGGL(xin_k, dim3((N2_ * 64 + 255) / 256), dim3(256), 0, stream, prot_x, t2d, Xin);

    // conv1: Xin(64) -> U [N2][128]
    {
        dim3 g(1, N2_ / 128), b(256);
        hipLaunchKernelGGL(gemm_bb_k, g, b, 0, stream, Xin, 64, WT_c1t, 64,
                           (const u16*)nullptr, U, 128, 0);
    }
    // agg(E): U -> V (width 128), drug partials -> Wacc, finalize
    hipMemsetAsync(Wacc, 0, B_ * 128 * sizeof(float), stream);
    hipLaunchKernelGGL((prot_agg_res_k<128>), dim3(N2_ / 16), dim3(256), 0, stream,
                       U, cPE, cNE, cDE, cSE, cInE, b_c1t, V, Wacc);
    hipLaunchKernelGGL(drug_fin_k, dim3(B_), dim3(128), 0, stream, Wacc, U, cSE, b_c1t, V, 128);
    // conv2: V(128) -> U [N2][256]
    gemm_n256(V, 128, WT_c2t, (const u16*)nullptr, U, 0, nullptr, nullptr, stream);
    // agg(E): U -> X (width 256)
    hipMemsetAsync(Wacc, 0, B_ * 256 * sizeof(float), stream);
    hipLaunchKernelGGL((prot_agg_res_k<256>), dim3(N2_ / 8), dim3(256), 0, stream,
                       U, cPE, cNE, cDE, cSE, cInE, b_c2t, X, Wacc);
    hipLaunchKernelGGL(drug_fin_k, dim3(B_), dim3(256), 0, stream, Wacc, U, cSE, b_c2t, X, 256);

    // 4 res-blocks:
    //   g (X->U, + Wacc epilogue), fused agg+l (U -> X, resid X, relu)
    for (int it = 0; it < 4; ++it) {
        hipMemsetAsync(Wacc, 0, B_ * 256 * sizeof(float), stream);
        gemm_n256(X, 256, WT_rtg, (const u16*)nullptr, U, 0, cInFO, Wacc, stream);
        {
            dim3 g(N2_ / 64), b(256);
            hipLaunchKernelGGL((gemm_aggl_k<8>), g, b, 0, stream,
                               U, WT_rtl, cPO, cNO, cDO, cSO, Wacc, b_rt_g, X, X);
        }
    }

    hipLaunchKernelGGL(x2g_bf2_k, dim3(B_), dim3(256), 0, stream, X, x2g, dafter);

    // ---------- heads (split-K fp32) ----------
    gemm_sk(x2g, W_fg1t, b_fg1t, t1t, skbuf, B_, 1024, 256, 8, 1, stream);
    gemm_sk(t1t, W_fg2t, b_fg2t, x2v, skbuf, B_, 256, 1024, 16, 0, stream);
    hipLaunchKernelGGL(build_xc_k, dim3(B_ * 512 / 256), dim3(256), 0, stream, dafter, x_chg, x2v, xc);
    gemm_sk(xc, W_fc1, b_fc1, f1, skbuf, B_, 1024, 512, 8, 1, stream);
    gemm_sk(f1, W_fc2, b_fc2, f2, skbuf, B_, 512, 1024, 16, 1, stream);
    hipLaunchKernelGGL(out_k, dim3(B_), dim3(64), 0, stream, f2, W_out, b_out, out);
}

// Round 15
// 1104.807 us; speedup vs baseline: 1.0160x; 1.0002x over previous
//
#include <hip/hip_runtime.h>
#include <cstdio>

// ---- problem constants (fixed by setup_inputs) ----
#define B_   256
#define L_   512
#define A_   40
#define FD_  78
#define FT_  54
#define LD_  128
#define P_   513            // L+1
#define ND_  (B_*A_)        // 10240 drug nodes
#define N2_  (B_*P_)        // 131328 protein nodes (= 1026*128, %128==0)
#define EB_  2046           // protein edges per batch: 2*(L-1)+2*L

typedef __attribute__((ext_vector_type(8))) short short8;
typedef __attribute__((ext_vector_type(4))) float floatx4;
typedef unsigned short u16;

__device__ __forceinline__ short f2bf(float f) {
    union { float f; unsigned u; } v; v.f = f;
    unsigned u = v.u;
    u += 0x7fff + ((u >> 16) & 1);   // round-to-nearest-even
    return (short)(u >> 16);
}
__device__ __forceinline__ float bf2f(u16 s) {
    union { unsigned u; float f; } v; v.u = ((unsigned)s) << 16; return v.f;
}

#define TBK 32
#define LDK 40   // LDS row stride in shorts: 80B (16B-aligned; 2-way bank alias free)
#define CSP 260  // fp32 epilogue-staging row stride (floats)

// LDS-only barrier: waits LDS ops, does NOT drain vmcnt -> global loads
// stay in flight across the barrier.  Correctness-verified rounds 6-14.
#define SYNC_LDS asm volatile("s_waitcnt lgkmcnt(0)\n\ts_barrier" ::: "memory")

// =====================================================================
// FUSED DRUG BRANCH (round-10/12 verified config: 512 threads, DR=20).
// Row-split: thread (half, col) computes 20 of the 40 rows of column
// col (acc[20]) -> 8 waves/block = 2 waves/SIMD.  r0 in {0,20} keeps
// the 20-float LDS reads 80B-aligned -> ds_read_b128 x5 (DR=10 broke
// alignment and doubled LDS instruction count: 218us vs 162us).
// Aggregation boundary (rows 19<->20) exchanged pre-agg via LDS.
// =====================================================================
#define DR_ 20
__global__ __launch_bounds__(512) void drug_fused_k(
    const float* __restrict__ drug_x,
    const float* __restrict__ W_c1d, const float* __restrict__ b_c1d,
    const float* __restrict__ W_c2d, const float* __restrict__ b_c2d,
    const float* __restrict__ W_rd_g, const float* __restrict__ b_rd_g,
    const float* __restrict__ W_rd_l,
    float* __restrict__ xg)
{
    __shared__ float Xb[2][156 * 40];      // 49.9 KB ping-pong, XT[k][r]
    __shared__ float bndA[256];            // pre-agg acc at row 19 (half 0)
    __shared__ float bndB[256];            // pre-agg acc at row 20 (half 1)
    const int b = blockIdx.x, t = threadIdx.x;
    const int col = t & 255, half = t >> 8;
    const int r0 = half * DR_;
    const float DI2 = 0.70710678118654752f;
    const float DI3 = 0.57735026918962576f;

    // stage drug_x[b] ([40][78] row-major) -> Xb[0] transposed
    for (int idx = t; idx < 40 * 78; idx += 512) {
        int r = idx / 78, k = idx - r * 78;
        Xb[0][k * 40 + r] = drug_x[(size_t)(b * A_ + r) * FD_ + k];
    }
    __syncthreads();

    float acc[DR_], hn[DR_];

    // acc[r] = sum_k XT[src][k][r0+r] * W[k][col]
    auto gemm_cols = [&](const float* __restrict__ Wp, int K, int N, int SRC) {
#pragma unroll
        for (int r = 0; r < DR_; ++r) acc[r] = 0.f;
        if (col < N) {
            for (int k = 0; k < K; ++k) {
                float w = Wp[(size_t)k * N + col];
                const float* xp = &Xb[SRC][k * 40 + r0];
#pragma unroll
                for (int r = 0; r < DR_; ++r)
                    acc[r] = fmaf(xp[r], w, acc[r]);
            }
        }
    };

    // graph agg (+bias, relu) with cross-half boundary exchange; store DST
    auto agg_store = [&](const float* __restrict__ bias, int N, int DST) {
        if (col < N) {
            if (half == 0) bndA[col] = acc[DR_ - 1];   // row 19
            else           bndB[col] = acc[0];         // row 20
        }
        __syncthreads();
        if (col < N) {
            float bi = bias[col];
#pragma unroll
            for (int r = 0; r < DR_; ++r) {
                int gr = r0 + r;
                float da = (gr == 0 || gr == A_ - 1) ? DI2 : DI3;
                float v = da * da * acc[r] + bi;
                if (gr > 0) {
                    float pv = (r > 0) ? acc[r - 1] : bndA[col];
                    v += ((gr - 1 == 0) ? DI2 : DI3) * da * pv;
                }
                if (gr < A_ - 1) {
                    float nv = (r < DR_ - 1) ? acc[r + 1] : bndB[col];
                    v += ((gr + 1 == A_ - 1) ? DI2 : DI3) * da * nv;
                }
                hn[r] = fmaxf(v, 0.f);
            }
#pragma unroll
            for (int r = 0; r < DR_; ++r) Xb[DST][col * 40 + r0 + r] = hn[r];
        }
        __syncthreads();
    };

    // conv1: 78 -> 78   (Xb0 -> Xb1)
    gemm_cols(W_c1d, FD_, FD_, 0);
    agg_store(b_c1d, FD_, 1);
    // conv2: 78 -> 156  (Xb1 -> Xb0)
    gemm_cols(W_c2d, FD_, 2 * FD_, 1);
    agg_store(b_c2d, 2 * FD_, 0);

    // 4 res-blocks
    for (int it = 0; it < 4; ++it) {
        gemm_cols(W_rd_g, 2 * FD_, 2 * FD_, 0);
        agg_store(b_rd_g, 2 * FD_, 1);
        gemm_cols(W_rd_l, 2 * FD_, 2 * FD_, 1);
        if (col < 2 * FD_) {
#pragma unroll
            for (int r = 0; r < DR_; ++r)
                hn[r] = fmaxf(acc[r] + Xb[0][col * 40 + r0 + r], 0.f);
        }
        __syncthreads();           // all reads of Xb0/Xb1 done
        if (col < 2 * FD_) {
#pragma unroll
            for (int r = 0; r < DR_; ++r) Xb[0][col * 40 + r0 + r] = hn[r];
        }
        __syncthreads();
    }

    // max-pool over 40 nodes (hn holds this thread's final rows)
    if (col < 2 * FD_) {
        float m = -INFINITY;
#pragma unroll
        for (int r = 0; r < DR_; ++r) m = fmaxf(m, hn[r]);
        if (half == 0) bndA[col] = m; else bndB[col] = m;
    }
    __syncthreads();
    if (half == 0 && col < 2 * FD_)
        xg[(size_t)b * (2 * FD_) + col] = fmaxf(bndA[col], bndB[col]);
}

// =====================================================================
// MFMA GEMM (fp32 A): C_fp32 = A[M,K]fp32 @ W (WT[N][Kp] bf16). For attention.
// (kept in the old staged form: K=54 tail needs the boundary guard)
// =====================================================================
__global__ __launch_bounds__(256) void gemm_mfma_k(
    const float* __restrict__ A, const short* __restrict__ WT,
    float* __restrict__ C, int M, int N, int K, int Kp)
{
    __shared__ short As[128 * LDK];
    __shared__ short Bs[128 * LDK];
    const int bm = blockIdx.y * 128;
    const int bn = blockIdx.x * 128;
    const int tid  = threadIdx.x;
    const int wave = tid >> 6, lane = tid & 63;
    const int wm = (wave >> 1) * 64, wn = (wave & 1) * 64;
    const int lrow = lane & 15, quad = lane >> 4;

    floatx4 acc[4][4] = {};

    for (int k0 = 0; k0 < Kp; k0 += TBK) {
#pragma unroll
        for (int it = 0; it < 2; ++it) {
            int g   = it * 256 + tid;
            int row = g >> 2, kg = g & 3;
            int kb  = k0 + kg * 8;
            const float* arow = A + (size_t)(bm + row) * K + kb;
            short8 av;
#pragma unroll
            for (int j = 0; j < 8; ++j) av[j] = (kb + j < K) ? f2bf(arow[j]) : (short)0;
            *(short8*)&As[row * LDK + kg * 8] = av;
            *(short8*)&Bs[row * LDK + kg * 8] = *(const short8*)(WT + (size_t)(bn + row) * Kp + kb);
        }
        __syncthreads();
        short8 af[4], bfv[4];
#pragma unroll
        for (int i = 0; i < 4; ++i)
            af[i] = *(short8*)&As[(wm + i * 16 + lrow) * LDK + quad * 8];
#pragma unroll
        for (int j = 0; j < 4; ++j)
            bfv[j] = *(short8*)&Bs[(wn + j * 16 + lrow) * LDK + quad * 8];
#pragma unroll
        for (int i = 0; i < 4; ++i)
#pragma unroll
            for (int j = 0; j < 4; ++j)
                acc[i][j] = __builtin_amdgcn_mfma_f32_16x16x32_bf16(af[i], bfv[j], acc[i][j], 0, 0, 0);
        __syncthreads();
    }
#pragma unroll
    for (int i = 0; i < 4; ++i) {
        int grow0 = bm + wm + i * 16 + quad * 4;
#pragma unroll
        for (int j = 0; j < 4; ++j) {
            int col = bn + wn + j * 16 + lrow;
            size_t base = (size_t)grow0 * N + col;
#pragma unroll
            for (int r = 0; r < 4; ++r)
                C[base + (size_t)r * N] = acc[i][j][r];
        }
    }
}

// =====================================================================
// conv1 GEMM, round-15: 64-row x 128-col tile, verified round-7/12
// template (full A-preload, direct-B fragments from L2-resident WT,
// SYNC_LDS barriers, staged coalesced epilogue).  K=64 exactly (Xin is
// zero-padded), N=128 exactly -> no boundary hazards.
// =====================================================================
__global__ __launch_bounds__(256, 2) void gemm_c1_k(
    const u16* __restrict__ A,      // Xin [N2][64] bf16
    const short* __restrict__ WT,   // WT_c1t [128][64] bf16
    u16* __restrict__ C)            // U [N2][128] bf16
{
    constexpr int K = 64;
    __shared__ short As[64 * LDK];      // 5 KB
    __shared__ float Cs[16 * CSP];      // 16.25 KB epilogue staging
    const int bm = blockIdx.x * 64;
    const int tid  = threadIdx.x;
    const int wave = tid >> 6, lane = tid & 63;
    const int wn = wave * 32;           // 4 waves x 32 cols = 128
    const int lrow = lane & 15, quad = lane >> 4;
    const int srow = tid >> 2, skg = tid & 3;

    floatx4 acc[4][2] = {};

    // full A preload (2 k-tiles)
    short8 aR[2];
#pragma unroll
    for (int kt = 0; kt < 2; ++kt)
        aR[kt] = *(const short8*)(A + (size_t)(bm + srow) * K + kt * TBK + skg * 8);

    // direct-B fragment pointers (WT is 16 KB, L2-resident)
    const short* bp0 = WT + (size_t)(wn +  0 + lrow) * K + quad * 8;
    const short* bp1 = WT + (size_t)(wn + 16 + lrow) * K + quad * 8;
    short8 bfv[2][2];
    bfv[0][0] = *(const short8*)bp0;
    bfv[0][1] = *(const short8*)bp1;

#pragma unroll
    for (int kt = 0; kt < 2; ++kt) {
        const int cur = kt & 1, nxt = cur ^ 1;
        *(short8*)&As[srow * LDK + skg * 8] = aR[kt];
        SYNC_LDS;
        if (kt + 1 < 2) {
            bfv[nxt][0] = *(const short8*)(bp0 + TBK);
            bfv[nxt][1] = *(const short8*)(bp1 + TBK);
        }
        short8 af[4];
#pragma unroll
        for (int i = 0; i < 4; ++i)
            af[i] = *(short8*)&As[(i * 16 + lrow) * LDK + quad * 8];
#pragma unroll
        for (int i = 0; i < 4; ++i) {
            acc[i][0] = __builtin_amdgcn_mfma_f32_16x16x32_bf16(af[i], bfv[cur][0], acc[i][0], 0, 0, 0);
            acc[i][1] = __builtin_amdgcn_mfma_f32_16x16x32_bf16(af[i], bfv[cur][1], acc[i][1], 0, 0, 0);
        }
        SYNC_LDS;
    }

    // staged C epilogue: fp32 LDS re-layout -> coalesced short8 stores
    const int erl = tid >> 4;          // 16 local rows
    const int ecc = (tid & 15) * 8;    // 16 x 8 = 128 cols
#pragma unroll
    for (int i = 0; i < 4; ++i) {
#pragma unroll
        for (int j = 0; j < 2; ++j)
#pragma unroll
            for (int r = 0; r < 4; ++r)
                Cs[(quad * 4 + r) * CSP + wn + j * 16 + lrow] = acc[i][j][r];
        SYNC_LDS;
        const int grow = bm + i * 16 + erl;
        const size_t gbase = (size_t)grow * 128 + ecc;
        const float* cp = &Cs[erl * CSP + ecc];
        short8 ov;
#pragma unroll
        for (int e = 0; e < 8; ++e) ov[e] = f2bf(cp[e]);
        *(short8*)(C + gbase) = ov;
        SYNC_LDS;
    }
}

// =====================================================================
// MFMA GEMM, 64x256 tile, N=256, K = KT*32.  Round-7/8/12 verified:
// direct-B fragments + SYNC_LDS barriers + staged coalesced epilogue.
// launch_bounds (256,2): (256,3) tested round-13, neutral-to-negative.
// Optional Wacc epilogue (drug-row partial sums).
// =====================================================================
template<int KT>
__global__ __launch_bounds__(256, 2) void gemm_n256pw_k(
    const u16* __restrict__ A, const short* __restrict__ WT,
    const u16* __restrict__ resid, u16* __restrict__ C, int act,
    const float* __restrict__ cInF, float* __restrict__ Wacc)
{
    constexpr int K = KT * TBK;
    __shared__ short As[64 * LDK];      // 5 KB
    __shared__ float Cs[16 * CSP];      // 16.25 KB epilogue staging
    const int bm = blockIdx.x * 64;
    const int tid  = threadIdx.x;
    const int wave = tid >> 6, lane = tid & 63;
    const int wn = wave * 64;
    const int lrow = lane & 15, quad = lane >> 4;
    const int srow = tid >> 2, skg = tid & 3;   // staging row / k-group

    floatx4 acc[4][4] = {};

    short8 aR[KT];
#pragma unroll
    for (int kt = 0; kt < KT; ++kt)
        aR[kt] = *(const short8*)(A + (size_t)(bm + srow) * K + kt * TBK + skg * 8);

    const short* bp0 = WT + (size_t)(wn +  0 + lrow) * K + quad * 8;
    const short* bp1 = WT + (size_t)(wn + 16 + lrow) * K + quad * 8;
    const short* bp2 = WT + (size_t)(wn + 32 + lrow) * K + quad * 8;
    const short* bp3 = WT + (size_t)(wn + 48 + lrow) * K + quad * 8;
    short8 bfv[2][4];
    bfv[0][0] = *(const short8*)bp0;
    bfv[0][1] = *(const short8*)bp1;
    bfv[0][2] = *(const short8*)bp2;
    bfv[0][3] = *(const short8*)bp3;

#pragma unroll
    for (int kt = 0; kt < KT; ++kt) {
        const int cur = kt & 1, nxt = cur ^ 1;
        *(short8*)&As[srow * LDK + skg * 8] = aR[kt];
        SYNC_LDS;
        if (kt + 1 < KT) {
            const int kn = (kt + 1) * TBK;
            bfv[nxt][0] = *(const short8*)(bp0 + kn);
            bfv[nxt][1] = *(const short8*)(bp1 + kn);
            bfv[nxt][2] = *(const short8*)(bp2 + kn);
            bfv[nxt][3] = *(const short8*)(bp3 + kn);
        }
        short8 af[4];
#pragma unroll
        for (int i = 0; i < 4; ++i)
            af[i] = *(short8*)&As[(i * 16 + lrow) * LDK + quad * 8];
#pragma unroll
        for (int i = 0; i < 4; ++i)
#pragma unroll
            for (int j = 0; j < 4; ++j)
                acc[i][j] = __builtin_amdgcn_mfma_f32_16x16x32_bf16(af[i], bfv[cur][j], acc[i][j], 0, 0, 0);
        SYNC_LDS;
    }

    if (cInF) {
        const int b0 = bm / P_;
        const int b1 = (bm + 63) / P_;
        float s0[4] = {0.f, 0.f, 0.f, 0.f};
        float s1[4] = {0.f, 0.f, 0.f, 0.f};
#pragma unroll
        for (int i = 0; i < 4; ++i) {
#pragma unroll
            for (int r = 0; r < 4; ++r) {
                int grow = bm + i * 16 + quad * 4 + r;
                float ci = cInF[grow];
                bool hi = (grow / P_) != b0;
#pragma unroll
                for (int j = 0; j < 4; ++j) {
                    float v = ci * acc[i][j][r];
                    if (hi) s1[j] += v; else s0[j] += v;
                }
            }
        }
#pragma unroll
        for (int j = 0; j < 4; ++j) {
            s0[j] += __shfl_xor(s0[j], 16);
            s0[j] += __shfl_xor(s0[j], 32);
            s1[j] += __shfl_xor(s1[j], 16);
            s1[j] += __shfl_xor(s1[j], 32);
        }
        if (quad == 0) {
#pragma unroll
            for (int j = 0; j < 4; ++j) {
                int col = wn + j * 16 + lrow;
                atomicAdd(&Wacc[(size_t)b0 * 256 + col], s0[j]);
                if (b1 != b0) atomicAdd(&Wacc[(size_t)b1 * 256 + col], s1[j]);
            }
        }
    }

    // staged C epilogue: fp32 LDS re-layout -> coalesced short8 IO
    const int erl = tid >> 4;
    const int ecc = (tid & 15) * 16;
#pragma unroll
    for (int i = 0; i < 4; ++i) {
#pragma unroll
        for (int j = 0; j < 4; ++j)
#pragma unroll
            for (int r = 0; r < 4; ++r)
                Cs[(quad * 4 + r) * CSP + wn + j * 16 + lrow] = acc[i][j][r];
        SYNC_LDS;
        const int grow = bm + i * 16 + erl;
        const size_t gbase = (size_t)grow * 256 + ecc;
#pragma unroll
        for (int h = 0; h < 2; ++h) {
            const float* cp = &Cs[erl * CSP + ecc + h * 8];
            short8 ov;
            if (resid) {
                short8 rv = *(const short8*)(resid + gbase + h * 8);
#pragma unroll
                for (int e = 0; e < 8; ++e) {
                    float v = cp[e] + bf2f((u16)rv[e]);
                    if (act) v = fmaxf(v, 0.f);
                    ov[e] = f2bf(v);
                }
            } else {
#pragma unroll
                for (int e = 0; e < 8; ++e) {
                    float v = cp[e];
                    if (act) v = fmaxf(v, 0.f);
                    ov[e] = f2bf(v);
                }
            }
            *(short8*)(C + gbase + h * 8) = ov;
        }
        SYNC_LDS;
    }
}

// =====================================================================
// Fused aggregation + l-GEMM (round-7/8/12 verified).
// =====================================================================
template<int KT>
__global__ __launch_bounds__(256, 2) void gemm_aggl_k(
    const u16* __restrict__ U, const short* __restrict__ WT,
    const float* __restrict__ cPc, const float* __restrict__ cNc,
    const float* __restrict__ cDc, const float* __restrict__ cSc,
    const float* __restrict__ Wacc, const float* __restrict__ bias,
    const u16* __restrict__ resid, u16* __restrict__ C)
{
    constexpr int K = KT * TBK;
    __shared__ short As[64 * LDK];      // 5 KB
    __shared__ float Cs[16 * CSP];      // 16.25 KB epilogue staging
    const int bm = blockIdx.x * 64;
    const int tid  = threadIdx.x;
    const int wave = tid >> 6, lane = tid & 63;
    const int wn = wave * 64;
    const int lrow = lane & 15, quad = lane >> 4;
    const int srow = tid >> 2, skg = tid & 3;

    const int r    = bm + srow;
    const int bl   = r / P_;
    const int irow = r - bl * P_;
    const bool isD = (irow == L_);
    const size_t rD = (size_t)bl * P_ + L_;
    const int rm = (r == 0) ? 0 : r - 1;            // cP==0 at i==0
    const int rp = (r == N2_ - 1) ? r : r + 1;      // cN==0 at i==L-1
    const float cs = cSc[r];
    const float cp = isD ? 0.f : cPc[r];
    const float cn = isD ? 0.f : cNc[r];
    const float cd = isD ? 0.f : cDc[r];
    const float* wrow = Wacc + (size_t)bl * 256;

    floatx4 acc[4][4] = {};

    const u16* uSp = U + (size_t)r  * K + skg * 8;
    const u16* uMp = U + (size_t)rm * K + skg * 8;
    const u16* uPp = U + (size_t)rp * K + skg * 8;
    const u16* uDp = U + rD * K + skg * 8;

    short8 uS[KT];
#pragma unroll
    for (int kt = 0; kt < KT; ++kt) uS[kt] = *(const short8*)(uSp + kt * TBK);
    short8 uM = *(const short8*)uMp;
    short8 uP = *(const short8*)uPp;
    short8 uD = *(const short8*)uDp;

    const short* bp0 = WT + (size_t)(wn +  0 + lrow) * K + quad * 8;
    const short* bp1 = WT + (size_t)(wn + 16 + lrow) * K + quad * 8;
    const short* bp2 = WT + (size_t)(wn + 32 + lrow) * K + quad * 8;
    const short* bp3 = WT + (size_t)(wn + 48 + lrow) * K + quad * 8;

#pragma unroll
    for (int kt = 0; kt < KT; ++kt) {
        const int kb = kt * TBK + skg * 8;
        float4 bi0 = *(const float4*)(bias + kb);
        float4 bi1 = *(const float4*)(bias + kb + 4);
        float bv[8] = {bi0.x, bi0.y, bi0.z, bi0.w, bi1.x, bi1.y, bi1.z, bi1.w};
        if (isD) {
            float4 w0 = *(const float4*)(wrow + kb);
            float4 w1 = *(const float4*)(wrow + kb + 4);
            bv[0] += w0.x; bv[1] += w0.y; bv[2] += w0.z; bv[3] += w0.w;
            bv[4] += w1.x; bv[5] += w1.y; bv[6] += w1.z; bv[7] += w1.w;
        }
        short8 av;
#pragma unroll
        for (int e = 0; e < 8; ++e) {
            float v = cs * bf2f((u16)uS[kt][e]) + cp * bf2f((u16)uM[e])
                    + cn * bf2f((u16)uP[e]) + cd * bf2f((u16)uD[e]) + bv[e];
            av[e] = f2bf(fmaxf(v, 0.f));
        }
        *(short8*)&As[srow * LDK + skg * 8] = av;
        const int kc = kt * TBK;
        short8 bfv0 = *(const short8*)(bp0 + kc);
        short8 bfv1 = *(const short8*)(bp1 + kc);
        short8 bfv2 = *(const short8*)(bp2 + kc);
        short8 bfv3 = *(const short8*)(bp3 + kc);
        SYNC_LDS;
        if (kt + 1 < KT) {
            const int kn = (kt + 1) * TBK;
            uM = *(const short8*)(uMp + kn);
            uP = *(const short8*)(uPp + kn);
            uD = *(const short8*)(uDp + kn);
        }
        short8 af[4];
#pragma unroll
        for (int i = 0; i < 4; ++i)
            af[i] = *(short8*)&As[(i * 16 + lrow) * LDK + quad * 8];
#pragma unroll
        for (int i = 0; i < 4; ++i) {
            acc[i][0] = __builtin_amdgcn_mfma_f32_16x16x32_bf16(af[i], bfv0, acc[i][0], 0, 0, 0);
            acc[i][1] = __builtin_amdgcn_mfma_f32_16x16x32_bf16(af[i], bfv1, acc[i][1], 0, 0, 0);
            acc[i][2] = __builtin_amdgcn_mfma_f32_16x16x32_bf16(af[i], bfv2, acc[i][2], 0, 0, 0);
            acc[i][3] = __builtin_amdgcn_mfma_f32_16x16x32_bf16(af[i], bfv3, acc[i][3], 0, 0, 0);
        }
        SYNC_LDS;
    }

    const int erl = tid >> 4;
    const int ecc = (tid & 15) * 16;
#pragma unroll
    for (int i = 0; i < 4; ++i) {
#pragma unroll
        for (int j = 0; j < 4; ++j)
#pragma unroll
            for (int r2 = 0; r2 < 4; ++r2)
                Cs[(quad * 4 + r2) * CSP + wn + j * 16 + lrow] = acc[i][j][r2];
        SYNC_LDS;
        const int grow = bm + i * 16 + erl;
        const size_t gbase = (size_t)grow * 256 + ecc;
#pragma unroll
        for (int h = 0; h < 2; ++h) {
            const float* cp2 = &Cs[erl * CSP + ecc + h * 8];
            short8 rv = *(const short8*)(resid + gbase + h * 8);
            short8 ov;
#pragma unroll
            for (int e = 0; e < 8; ++e) {
                float v = cp2[e] + bf2f((u16)rv[e]);
                ov[e] = f2bf(fmaxf(v, 0.f));
            }
            *(short8*)(C + gbase + h * 8) = ov;
        }
        SYNC_LDS;
    }
}

static inline void gemm_n256(const u16* A, int K, const short* WT,
                             const u16* resid, u16* C, int act,
                             const float* cInF, float* Wacc, hipStream_t s)
{
    dim3 g(N2_ / 64), b(256);
    if (K == 128)
        hipLaunchKernelGGL((gemm_n256pw_k<4>), g, b, 0, s, A, WT, resid, C, act, cInF, Wacc);
    else
        hipLaunchKernelGGL((gemm_n256pw_k<8>), g, b, 0, s, A, WT, resid, C, act, cInF, Wacc);
}

// one-time weight transpose+cast: WT[n*Kp+k] = bf16(W[k*Nreal+n]), zero padded
__global__ void wt_cvt_k(const float* __restrict__ W, short* __restrict__ WT,
                         int K, int Nreal, int Kp, int Ntot)
{
    int idx = blockIdx.x * 256 + threadIdx.x;
    if (idx >= Ntot * Kp) return;
    int n = idx / Kp, k = idx - n * Kp;
    WT[idx] = (k < K && n < Nreal) ? f2bf(W[(size_t)k * Nreal + n]) : (short)0;
}

// =====================================================================
// Split-K fp32 GEMM for small-M (M=256) head GEMMs.
// =====================================================================
#define BM 64
#define BN 64
#define BKK 16
__global__ __launch_bounds__(256) void gemm_skA_k(
    const float* __restrict__ Amat, const float* __restrict__ Wmat,
    float* __restrict__ part, int M, int N, int K, int Kc)
{
    __shared__ float As[BKK][BM + 4];
    __shared__ float Ws[BKK][BN];
    const int bm = blockIdx.y * BM;
    const int bn = blockIdx.x * BN;
    const int sk = blockIdx.z;
    const int kb0  = sk * Kc;
    const int kend = min(K, kb0 + Kc);
    const int tx = threadIdx.x, ty = threadIdx.y;
    const int tid = ty * 16 + tx;
    float acc[4][4] = {};

    for (int k0 = kb0; k0 < kend; k0 += BKK) {
#pragma unroll
        for (int j = 0; j < 4; ++j) {
            int l = tid + 256 * j;
            int m = l >> 4, kk = l & 15;
            int gm = bm + m, gk = k0 + kk;
            As[kk][m] = (gm < M && gk < kend) ? Amat[(size_t)gm * K + gk] : 0.f;
        }
#pragma unroll
        for (int j = 0; j < 4; ++j) {
            int l = tid + 256 * j;
            int kk = l >> 6, n = l & 63;
            int gk = k0 + kk, gn = bn + n;
            Ws[kk][n] = (gk < kend && gn < N) ? Wmat[(size_t)gk * N + gn] : 0.f;
        }
        __syncthreads();
#pragma unroll
        for (int k = 0; k < BKK; ++k) {
            float4 a4 = *(const float4*)&As[k][ty * 4];
            float4 w4 = *(const float4*)&Ws[k][tx * 4];
            float av[4] = {a4.x, a4.y, a4.z, a4.w};
            float wv[4] = {w4.x, w4.y, w4.z, w4.w};
#pragma unroll
            for (int i = 0; i < 4; ++i)
#pragma unroll
                for (int j = 0; j < 4; ++j)
                    acc[i][j] = fmaf(av[i], wv[j], acc[i][j]);
        }
        __syncthreads();
    }
#pragma unroll
    for (int i = 0; i < 4; ++i) {
        int gm = bm + ty * 4 + i;
        if (gm >= M) continue;
#pragma unroll
        for (int j = 0; j < 4; ++j) {
            int gn = bn + tx * 4 + j;
            if (gn >= N) continue;
            part[((size_t)sk * M + gm) * N + gn] = acc[i][j];
        }
    }
}

__global__ void gemm_skB_k(const float* __restrict__ part, const float* __restrict__ bias,
                           float* __restrict__ C, int M, int N, int SK, int act)
{
    int idx = blockIdx.x * 256 + threadIdx.x;
    if (idx >= M * N) return;
    int n = idx % N;
    float v = bias ? bias[n] : 0.f;
    for (int s = 0; s < SK; ++s) v += part[(size_t)s * M * N + idx];
    if (act) v = fmaxf(v, 0.f);
    C[idx] = v;
}

static inline void gemm_sk(const float* A, const float* W, const float* bias,
                           float* C, float* skbuf, int M, int N, int K, int SK, int act,
                           hipStream_t s)
{
    int Kc = (K + SK - 1) / SK;
    dim3 g((N + 63) / 64, (M + 63) / 64, SK), b(16, 16);
    hipLaunchKernelGGL(gemm_skA_k, g, b, 0, s, A, W, skbuf, M, N, K, Kc);
    hipLaunchKernelGGL(gemm_skB_k, dim3((M * N + 255) / 256), dim3(256), 0, s,
                       skbuf, bias, C, M, N, SK, act);
}

// =====================================================================
// Attention epilogue + softmax
// =====================================================================
__global__ __launch_bounds__(256) void att_dot_k(
    const float* __restrict__ Hs, const float* __restrict__ b1,
    const float* __restrict__ W2, const float* __restrict__ b2,
    float* __restrict__ scores)
{
    int w = threadIdx.x >> 6, lane = threadIdx.x & 63;
    float b1v = (lane < FT_) ? b1[lane] : 0.f;
    float w2v = (lane < FT_) ? W2[lane] : 0.f;
    float b2v = b2[0];
    int base = blockIdx.x * 64 + w * 16;
    for (int rr = 0; rr < 16; ++rr) {
        int r = base + rr;
        float v = 0.f;
        if (lane < FT_) v = tanhf(Hs[(size_t)r * 128 + lane] + b1v) * w2v;
#pragma unroll
        for (int o = 32; o; o >>= 1) v += __shfl_down(v, o);
        if (lane == 0) {
            int bl = r / P_, i = r - bl * P_;
            if (i < L_) scores[bl * L_ + i] = v + b2v;
        }
    }
}

__global__ __launch_bounds__(512) void softmax_k(
    const float* __restrict__ scores, float* __restrict__ att, float* __restrict__ attsum)
{
    int b = blockIdx.x, t = threadIdx.x;
    __shared__ float sm[8];
    __shared__ float bcast;
    float v = scores[b * L_ + t];
    float m = v;
#pragma unroll
    for (int o = 32; o; o >>= 1) m = fmaxf(m, __shfl_down(m, o));
    if ((t & 63) == 0) sm[t >> 6] = m;
    __syncthreads();
    if (t == 0) { float mm = sm[0]; for (int i = 1; i < 8; ++i) mm = fmaxf(mm, sm[i]); bcast = mm; }
    __syncthreads();
    float mx = bcast;
    float e = expf(v - mx);
    float s = e;
#pragma unroll
    for (int o = 32; o; o >>= 1) s += __shfl_down(s, o);
    __syncthreads();
    if ((t & 63) == 0) sm[t >> 6] = s;
    __syncthreads();
    if (t == 0) { float ss = 0; for (int i = 0; i < 8; ++i) ss += sm[i]; bcast = ss; }
    __syncthreads();
    float a = e / bcast;
    att[b * L_ + t] = a;
    float s2 = a;
#pragma unroll
    for (int o = 32; o; o >>= 1) s2 += __shfl_down(s2, o);
    __syncthreads();
    if ((t & 63) == 0) sm[t >> 6] = s2;
    __syncthreads();
    if (t == 0) { float ss = 0; for (int i = 0; i < 8; ++i) ss += sm[i]; attsum[b] = ss; }
}

// =====================================================================
// Protein GCN coefficients
// =====================================================================
__global__ void coef_deg_k(const float* __restrict__ prot_ea, const float* __restrict__ att,
                           const float* __restrict__ attsum, float* __restrict__ dinv, int use_ea)
{
    int r = blockIdx.x * 256 + threadIdx.x;
    if (r >= N2_) return;
    int b = r / P_, i = r - b * P_;
    float deg;
    if (i == L_) {
        deg = 1.f + (use_ea ? attsum[b] : (float)L_);
    } else {
        float wP = (i >= 1)      ? (use_ea ? prot_ea[b * EB_ + (i - 1)]   : 1.f) : 0.f;
        float wN = (i <= L_ - 2) ? (use_ea ? prot_ea[b * EB_ + 511 + i]   : 1.f) : 0.f;
        float wD = use_ea ? att[b * L_ + i] : 1.f;
        deg = 1.f + wP + wN + wD;
    }
    dinv[r] = rsqrtf(deg);
}

__global__ void coef_k(const float* __restrict__ dinv, const float* __restrict__ prot_ea,
                       const float* __restrict__ att, float* __restrict__ cP, float* __restrict__ cN,
                       float* __restrict__ cD, float* __restrict__ cS, float* __restrict__ cIn,
                       float* __restrict__ cInF, int use_ea)
{
    int r = blockIdx.x * 256 + threadIdx.x;
    if (r >= N2_) return;
    int b = r / P_, i = r - b * P_;
    float di = dinv[r];
    cS[r] = di * di;
    if (i == L_) { cP[r] = 0.f; cN[r] = 0.f; cD[r] = 0.f; cInF[r] = 0.f; return; }
    float wP = (i >= 1)      ? (use_ea ? prot_ea[b * EB_ + (i - 1)] : 1.f) : 0.f;
    float wN = (i <= L_ - 2) ? (use_ea ? prot_ea[b * EB_ + 511 + i] : 1.f) : 0.f;
    float wD = use_ea ? att[b * L_ + i] : 1.f;
    float dD = dinv[b * P_ + L_];
    cP[r] = (i >= 1)      ? dinv[r - 1] * wP * di : 0.f;
    cN[r] = (i <= L_ - 2) ? dinv[r + 1] * wN * di : 0.f;
    cD[r] = dD * wD * di;
    float ci = di * wD * dD;
    cIn[b * L_ + i] = ci;
    cInF[r] = ci;
}

// =====================================================================
// Vectorized protein aggregation (bf16 in/out, fp32 math), short8 loads.
// (used for conv1/conv2 aggregation)
// =====================================================================
template<int F>
__global__ __launch_bounds__(256) void prot_agg_res_k(
    const u16* __restrict__ h, const float* __restrict__ cP,
    const float* __restrict__ cN, const float* __restrict__ cD,
    const float* __restrict__ cS, const float* __restrict__ cIn,
    const float* __restrict__ bias, u16* __restrict__ outp,
    float* __restrict__ Wacc)
{
    constexpr int G = F / 8;
    constexpr int RPB = 256 / G;
    __shared__ float pacc[RPB * F];     // 8 KB
    int t = threadIdx.x;
    int rl = t / G, g = t - rl * G;
    int base = blockIdx.x * RPB;
    int r = base + rl;
    int bl = r / P_, i = r - bl * P_;
    int f0 = g * 8;
    const u16* hs = h + (size_t)r * F + f0;
    if (i == L_) {
#pragma unroll
        for (int e = 0; e < 8; ++e) pacc[rl * F + f0 + e] = 0.f;
    } else {
        const u16* hd = h + ((size_t)bl * P_ + L_) * F + f0;
        float cs = cS[r], cd = cD[r], cp = cP[r], cn = cN[r];
        float ci = cIn[bl * L_ + i];
        short8 vs = *(const short8*)hs;
        short8 vd = *(const short8*)hd;
        short8 vp = *(const short8*)(hs - (i > 0 ? F : 0));   // cp==0 at i==0
        short8 vn = *(const short8*)(hs + F);                  // cn==0 at i==L-1
        short8 ov;
#pragma unroll
        for (int e = 0; e < 8; ++e) {
            float hv = bf2f((u16)vs[e]);
            pacc[rl * F + f0 + e] = ci * hv;
            float v = cs * hv + cd * bf2f((u16)vd[e]) + bias[f0 + e];
            v += cp * bf2f((u16)vp[e]);
            v += cn * bf2f((u16)vn[e]);
            ov[e] = f2bf(fmaxf(v, 0.f));
        }
        *(short8*)(outp + (size_t)r * F + f0) = ov;
    }
    __syncthreads();
    int f = t;
    if (f < F) {
        int b0   = base / P_;
        int bend = (base + RPB - 1) / P_;
        float s0 = 0.f, s1 = 0.f;
#pragma unroll
        for (int rr = 0; rr < RPB; ++rr) {
            float v = pacc[rr * F + f];
            if ((base + rr) / P_ == b0) s0 += v; else s1 += v;
        }
        atomicAdd(&Wacc[(size_t)b0 * F + f], s0);
        if (bend != b0) atomicAdd(&Wacc[(size_t)bend * F + f], s1);
    }
}

// finalize drug rows: V[drug] = relu(Wacc + cS*h[drug] + bias)
__global__ void drug_fin_k(const float* __restrict__ Wacc, const u16* __restrict__ h,
                           const float* __restrict__ cS, const float* __restrict__ bias,
                           u16* __restrict__ outp, int F)
{
    int bl = blockIdx.x, t = threadIdx.x;
    if (t >= F) return;
    size_t rD = (size_t)bl * P_ + L_;
    float v = Wacc[(size_t)bl * F + t] + cS[rD] * bf2f(h[rD * F + t]) + bias[t];
    outp[rD * F + t] = (u16)f2bf(fmaxf(v, 0.f));
}

// build bf16 conv1 input: Xin[N2][64], cols<54 = prot_x (drug rows from t2d), else 0
__global__ void xin_k(const float* __restrict__ prot_x, const float* __restrict__ t2d,
                      u16* __restrict__ Xin)
{
    int idx = blockIdx.x * 256 + threadIdx.x;
    if (idx >= N2_ * 64) return;
    int r = idx >> 6, t = idx & 63;
    int bl = r / P_, i = r - bl * P_;
    float v = 0.f;
    if (t < FT_) v = (i == L_) ? t2d[bl * FT_ + t] : prot_x[(size_t)r * FT_ + t];
    Xin[idx] = (u16)f2bf(v);
}

// per-batch max over residues + drug row extraction (vectorized, F=256)
__global__ __launch_bounds__(256) void x2g_bf2_k(const u16* __restrict__ X,
                                                 float* __restrict__ x2g, float* __restrict__ da)
{
    __shared__ float red[2048];
    int t = threadIdx.x;
    int rl = t >> 5, g = t & 31;
    int bl = blockIdx.x, f0 = g * 8;
    const u16* xb = X + (size_t)bl * P_ * 256;
    float m[8];
#pragma unroll
    for (int e = 0; e < 8; ++e) m[e] = -INFINITY;
    for (int j = rl; j < L_; j += 8) {
        short8 v = *(const short8*)(xb + (size_t)j * 256 + f0);
#pragma unroll
        for (int e = 0; e < 8; ++e) m[e] = fmaxf(m[e], bf2f((u16)v[e]));
    }
#pragma unroll
    for (int e = 0; e < 8; ++e) red[rl * 256 + f0 + e] = m[e];
    __syncthreads();
    if (rl == 0) {
        short8 vd = *(const short8*)(xb + (size_t)L_ * 256 + f0);
#pragma unroll
        for (int e = 0; e < 8; ++e) {
            float v = red[f0 + e];
            for (int rr = 1; rr < 8; ++rr) v = fmaxf(v, red[rr * 256 + f0 + e]);
            x2g[bl * 256 + f0 + e] = v;
            da[bl * 256 + f0 + e] = bf2f((u16)vd[e]);
        }
    }
}

__global__ void build_xc_k(const float* __restrict__ da, const float* __restrict__ x_chg,
                           const float* __restrict__ x2v, float* __restrict__ xc)
{
    int idx = blockIdx.x * 256 + threadIdx.x;
    if (idx >= B_ * 512) return;
    int b = idx >> 9, c = idx & 511;
    float v = (c < 256) ? fmaxf(da[b * 256 + c], x_chg[b * 256 + c])
                        : x2v[b * 256 + (c - 256)];
    xc[idx] = v;
}

__global__ __launch_bounds__(64) void out_k(const float* __restrict__ f2,
                                            const float* __restrict__ W,
                                            const float* __restrict__ bias,
                                            float* __restrict__ out)
{
    int row = blockIdx.x, t = threadIdx.x;
    float v = 0.f;
    for (int k = t; k < 512; k += 64) v = fmaf(f2[(size_t)row * 512 + k], W[k], v);
#pragma unroll
    for (int o = 32; o; o >>= 1) v += __shfl_down(v, o);
    if (t == 0) out[row] = v + bias[0];
}

// =====================================================================
extern "C" void kernel_launch(void* const* d_in, const int* in_sizes, int n_in,
                              void* d_out, int out_size, void* d_ws, size_t ws_size,
                              hipStream_t stream)
{
    const float* drug_x  = (const float*)d_in[0];
    const float* prot_x  = (const float*)d_in[3];
    const float* prot_ea = (const float*)d_in[6];
    const float* W_c1d = (const float*)d_in[7];   const float* b_c1d = (const float*)d_in[8];
    const float* W_c2d = (const float*)d_in[9];   const float* b_c2d = (const float*)d_in[10];
    const float* W_rd_g = (const float*)d_in[11]; const float* b_rd_g = (const float*)d_in[12];
    const float* W_rd_l = (const float*)d_in[13];
    const float* W_fg1d = (const float*)d_in[14]; const float* b_fg1d = (const float*)d_in[15];
    const float* W_fg2d = (const float*)d_in[16]; const float* b_fg2d = (const float*)d_in[17];
    const float* W_fg3d = (const float*)d_in[18]; const float* b_fg3d = (const float*)d_in[19];
    const float* W_att1 = (const float*)d_in[20]; const float* b_att1 = (const float*)d_in[21];
    const float* W_att2 = (const float*)d_in[22]; const float* b_att2 = (const float*)d_in[23];
    const float* W_c1t = (const float*)d_in[24];  const float* b_c1t = (const float*)d_in[25];
    const float* W_c2t = (const float*)d_in[26];  const float* b_c2t = (const float*)d_in[27];
    const float* W_rt_g = (const float*)d_in[28]; const float* b_rt_g = (const float*)d_in[29];
    const float* W_rt_l = (const float*)d_in[30];
    const float* W_fg1t = (const float*)d_in[31]; const float* b_fg1t = (const float*)d_in[32];
    const float* W_fg2t = (const float*)d_in[33]; const float* b_fg2t = (const float*)d_in[34];
    const float* W_fc1 = (const float*)d_in[35];  const float* b_fc1 = (const float*)d_in[36];
    const float* W_fc2 = (const float*)d_in[37];  const float* b_fc2 = (const float*)d_in[38];
    const float* W_out = (const float*)d_in[39];  const float* b_out = (const float*)d_in[40];
    float* out = (float*)d_out;

    float* ws = (float*)d_ws;
    size_t off = 0;
    auto alloc = [&](size_t n) {
        n = (n + 3) & ~(size_t)3;          // 16B alignment
        float* p = ws + off; off += n; return p;
    };

    // big bf16 activation buffers (full batch, width up to 256): 67.2 MB each
    u16* U = (u16*)alloc((size_t)N2_ * 128);
    u16* V = (u16*)alloc((size_t)N2_ * 128);
    u16* X = (u16*)alloc((size_t)N2_ * 128);
    u16* Xin = (u16*)alloc((size_t)N2_ * 32);    // [N2][64] bf16
    float* Hs = (float*)U;                        // fp32 attention scratch aliases U
    float* Wacc = alloc(B_ * 256);                // drug-row partial sums (fp32)
    float* xg    = alloc(B_ * 156);
    float* t1d   = alloc(B_ * 1024);
    float* t2d   = alloc(B_ * FT_);
    float* x_chg = alloc(B_ * 256);
    float* scores = alloc(B_ * 512);
    float* att    = alloc(B_ * 512);
    float* attsum = alloc(B_);
    float* dinvE = alloc(N2_);
    float* cPE = alloc(N2_); float* cNE = alloc(N2_); float* cDE = alloc(N2_); float* cSE = alloc(N2_);
    float* cInE = alloc(B_ * 512);
    float* cInFE = alloc(N2_);
    float* dinvO = alloc(N2_);
    float* cPO = alloc(N2_); float* cNO = alloc(N2_); float* cDO = alloc(N2_); float* cSO = alloc(N2_);
    float* cInO = alloc(B_ * 512);
    float* cInFO = alloc(N2_);
    float* x2g = alloc(B_ * 256);
    float* dafter = alloc(B_ * 256);
    float* t1t = alloc(B_ * 1024);
    float* x2v = alloc(B_ * 256);
    float* xc  = alloc(B_ * 512);
    float* f1  = alloc(B_ * 1024);
    float* f2  = alloc(B_ * 512);
    float* skbuf = alloc((size_t)2 * 1024 * 1024);
    // bf16 transposed weights
    short* WT_c1t = (short*)alloc(128 * 64 / 2);
    short* WT_c2t = (short*)alloc(256 * 128 / 2);
    short* WT_rtg = (short*)alloc(256 * 256 / 2);
    short* WT_rtl = (short*)alloc(256 * 256 / 2);
    short* WT_att = (short*)alloc(128 * 64 / 2);

    if (off * sizeof(float) > ws_size) {
        fprintf(stderr, "kernel_launch: workspace too small: need %zu, have %zu\n",
                off * sizeof(float), ws_size);
        return;
    }

    // ---------- one-time weight cast/transpose ----------
    hipLaunchKernelGGL(wt_cvt_k, dim3((128 * 64 + 255) / 256), dim3(256), 0, stream,  W_c1t, WT_c1t, FT_, 128, 64, 128);
    hipLaunchKernelGGL(wt_cvt_k, dim3((256 * 128 + 255) / 256), dim3(256), 0, stream, W_c2t, WT_c2t, 128, 256, 128, 256);
    hipLaunchKernelGGL(wt_cvt_k, dim3((256 * 256 + 255) / 256), dim3(256), 0, stream, W_rt_g, WT_rtg, 256, 256, 256, 256);
    hipLaunchKernelGGL(wt_cvt_k, dim3((256 * 256 + 255) / 256), dim3(256), 0, stream, W_rt_l, WT_rtl, 256, 256, 256, 256);
    hipLaunchKernelGGL(wt_cvt_k, dim3((128 * 64 + 255) / 256), dim3(256), 0, stream,  W_att1, WT_att, FT_, FT_, 64, 128);

    // ---------- drug branch: ONE fused kernel (10 layers + max-pool) ----------
    hipLaunchKernelGGL(drug_fused_k, dim3(B_), dim3(512), 0, stream,
                       drug_x, W_c1d, b_c1d, W_c2d, b_c2d, W_rd_g, b_rd_g, W_rd_l, xg);
    gemm_sk(xg,  W_fg1d, b_fg1d, t1d,   skbuf, B_, 1024, 156, 4, 1, stream);
    gemm_sk(t1d, W_fg2d, b_fg2d, t2d,   skbuf, B_, FT_, 1024, 16, 0, stream);
    gemm_sk(t2d, W_fg3d, b_fg3d, x_chg, skbuf, B_, 2 * LD_, FT_, 2, 1, stream);

    // ---------- attention (MFMA) ----------
    {
        dim3 g(1, N2_ / 128), b(256);
        hipLaunchKernelGGL(gemm_mfma_k, g, b, 0, stream, prot_x, WT_att, Hs, N2_, 128, FT_, 64);
    }
    hipLaunchKernelGGL(att_dot_k, dim3(N2_ / 64), dim3(256), 0, stream, Hs, b_att1, W_att2, b_att2, scores);
    hipLaunchKernelGGL(softmax_k, dim3(B_), dim3(512), 0, stream, scores, att, attsum);

    // ---------- protein GCN coefficients ----------
    hipLaunchKernelGGL(coef_deg_k, dim3((N2_ + 255) / 256), dim3(256), 0, stream, prot_ea, att, attsum, dinvE, 1);
    hipLaunchKernelGGL(coef_k, dim3((N2_ + 255) / 256), dim3(256), 0, stream, dinvE, prot_ea, att, cPE, cNE, cDE, cSE, cInE, cInFE, 1);
    hipLaunchKernelGGL(coef_deg_k, dim3((N2_ + 255) / 256), dim3(256), 0, stream, prot_ea, att, attsum, dinvO, 0);
    hipLaunchKernelGGL(coef_k, dim3((N2_ + 255) / 256), dim3(256), 0, stream, dinvO, prot_ea, att, cPO, cNO, cDO, cSO, cInO, cInFO, 0);

    // ---------- protein branch (full batch, bf16 activations) ----------
    hipLaunchKernelGGL(xin_k, dim3((N2_ * 64 + 255) / 256), dim3(256), 0, stream, prot_x, t2d, Xin);

    // conv1: Xin(64) -> U [N2][128]  (round-15: verified direct-B template)
    hipLaunchKernelGGL(gemm_c1_k, dim3(N2_ / 64), dim3(256), 0, stream, Xin, WT_c1t, U);
    // agg(E): U -> V (width 128), drug partials -> Wacc, finalize
    hipMemsetAsync(Wacc, 0, B_ * 128 * sizeof(float), stream);
    hipLaunchKernelGGL((prot_agg_res_k<128>), dim3(N2_ / 16), dim3(256), 0, stream,
                       U, cPE, cNE, cDE, cSE, cInE, b_c1t, V, Wacc);
    hipLaunchKernelGGL(drug_fin_k, dim3(B_), dim3(128), 0, stream, Wacc, U, cSE, b_c1t, V, 128);
    // conv2: V(128) -> U [N2][256]
    gemm_n256(V, 128, WT_c2t, (const u16*)nullptr, U, 0, nullptr, nullptr, stream);
    // agg(E): U -> X (width 256)
    hipMemsetAsync(Wacc, 0, B_ * 256 * sizeof(float), stream);
    hipLaunchKernelGGL((prot_agg_res_k<256>), dim3(N2_ / 8), dim3(256), 0, stream,
                       U, cPE, cNE, cDE, cSE, cInE, b_c2t, X, Wacc);
    hipLaunchKernelGGL(drug_fin_k, dim3(B_), dim3(256), 0, stream, Wacc, U, cSE, b_c2t, X, 256);

    // 4 res-blocks:
    //   g (X->U, + Wacc epilogue), fused agg+l (U -> X, resid X, relu)
    for (int it = 0; it < 4; ++it) {
        hipMemsetAsync(Wacc, 0, B_ * 256 * sizeof(float), stream);
        gemm_n256(X, 256, WT_rtg, (const u16*)nullptr, U, 0, cInFO, Wacc, stream);
        {
            dim3 g(N2_ / 64), b(256);
            hipLaunchKernelGGL((gemm_aggl_k<8>), g, b, 0, stream,
                               U, WT_rtl, cPO, cNO, cDO, cSO, Wacc, b_rt_g, X, X);
        }
    }

    hipLaunchKernelGGL(x2g_bf2_k, dim3(B_), dim3(256), 0, stream, X, x2g, dafter);

    // ---------- heads (split-K fp32) ----------
    gemm_sk(x2g, W_fg1t, b_fg1t, t1t, skbuf, B_, 1024, 256, 8, 1, stream);
    gemm_sk(t1t, W_fg2t, b_fg2t, x2v, skbuf, B_, 256, 1024, 16, 0, stream);
    hipLaunchKernelGGL(build_xc_k, dim3(B_ * 512 / 256), dim3(256), 0, stream, dafter, x_chg, x2v, xc);
    gemm_sk(xc, W_fc1, b_fc1, f1, skbuf, B_, 1024, 512, 8, 1, stream);
    gemm_sk(f1, W_fc2, b_fc2, f2, skbuf, B_, 512, 1024, 16, 1, stream);
    hipLaunchKernelGGL(out_k, dim3(B_), dim3(64), 0, stream, f2, W_out, b_out, out);
}